// Round 4
// baseline (17939.989 us; speedup 1.0000x reference)
//
#include <hip/hip_runtime.h>

// ---------------------------------------------------------------------------
// ADRNN persistent version (plain launch, manual grid barrier).
// One kernel, 131 blocks x 256 threads (co-resident: 131 <= 256 CUs,
// __launch_bounds__(256,2) caps VGPR at 256 -> >=2 blocks/CU capacity).
// Loops k=0..516 ("ticks") with a sense-reversing grid barrier between ticks.
// Stage pipeline (identical to the R1-proven decomposition):
//   tick k: r0(t=k) | r1(k-1) | rout(k-2) | t0(k-3) | t1(k-4) | tout(k-5)
// Cross-stage tensors parity double-buffered; every producer->consumer edge
// is exactly one tick (one barrier). fp16 MFMA 16x16x32, fp32 accumulate.
// Weights pre-converted to fp16 [n][k] (native B-fragment layout).
// ---------------------------------------------------------------------------

typedef _Float16 half_t;
typedef _Float16 half8 __attribute__((ext_vector_type(8)));
typedef float floatx4 __attribute__((ext_vector_type(4)));

// half-unit offsets inside d_ws
#define OFF_W0 0        // r_Wih0 padded  [2048][64]
#define OFF_W1 131072   // r_Whh0         [2048][512]
#define OFF_W2 1179648  // r_Wih1         [2048][512]
#define OFF_W3 2228224  // r_Whh1         [2048][512]
#define OFF_W4 3276800  // t_Wih0 cols0-48 padded [2048][64]
#define OFF_W5 3407872  // t_Wih0 cols49-95 padded [2048][64]
#define OFF_W6 3538944  // t_Whh0         [2048][512]
#define OFF_W7 4587520  // t_Wih1         [2048][512]
#define OFF_W8 5636096  // t_Whh1         [2048][512]
#define OFF_W9 6684672  // Wr padded      [48][512]
#define OFF_W10 6709248 // Wt padded      [16][512]
#define W_TOTAL 6717440
#define H_BASE  6717440              // h[4 cells][2 par][128][512] halves
#define RO_BASE 7241728              // rout16[2 par][128][64] halves
#define HALF_TOTAL 7258112
// byte offsets
#define STATE_BYTE_OFF (H_BASE * 2)          // 13434880
#define C_BYTE_OFF (HALF_TOTAL * 2)          // 14516224 (c: 4x[128][512] f32)
#define BAR_BYTE_OFF 15564800                // barrier state (512 B)
#define X16_BYTE_OFF 15565312                // optional x16 [512][128][64]
#define WS_NEED_X16 (15565312ull + 8388608ull)
#define STATE_BYTES (X16_BYTE_OFF - STATE_BYTE_OFF)  // h+ro+c+barrier

#define NBLK 131
#define TOUT_BASE (128 * 512 * 47)

__device__ __forceinline__ floatx4 mfma16(half8 a, half8 b, floatx4 c) {
  return __builtin_amdgcn_mfma_f32_16x16x32_f16(a, b, c, 0, 0, 0);
}

__device__ __forceinline__ float fast_sig(float x) {
  x = fminf(fmaxf(x, -30.f), 30.f);
  float e = __expf(-x);
  return __builtin_amdgcn_rcpf(1.f + e);
}
__device__ __forceinline__ float fast_tanh(float x) {
  x = fminf(fmaxf(x, -15.f), 15.f);
  float e = __expf(-2.f * x);
  return (1.f - e) * __builtin_amdgcn_rcpf(1.f + e);
}

// Wave computes MT m-tiles x NT n-tiles over K. Fragment layouts (16x16x32):
//  A[m][k]: lane l holds m=l&15, k=(l>>4)*8+j  -> 16B contiguous load
//  B[k][n]: lane l holds n=l&15, k=(l>>4)*8+j  -> W[n][k] row-major 16B load
template <int MT, int NT, int K>
__device__ __forceinline__ void gemm_h(const half_t* __restrict__ A, int lda,
                                       const half_t* __restrict__ W, int ldw,
                                       const int* wrow, int m0, int lane,
                                       floatx4 (&acc)[MT][NT]) {
  const int lk = (lane >> 4) * 8;
  const int l15 = lane & 15;
#pragma unroll 2
  for (int ks = 0; ks < K / 32; ++ks) {
    const int kb = ks * 32 + lk;
    half8 a[MT], b[NT];
#pragma unroll
    for (int mt = 0; mt < MT; ++mt)
      a[mt] = *(const half8*)(A + (long)(m0 + mt * 16 + l15) * lda + kb);
#pragma unroll
    for (int nt = 0; nt < NT; ++nt)
      b[nt] = *(const half8*)(W + (long)(wrow[nt] + l15) * ldw + kb);
#pragma unroll
    for (int mt = 0; mt < MT; ++mt)
#pragma unroll
      for (int nt = 0; nt < NT; ++nt)
        acc[mt][nt] = mfma16(a[mt], b[nt], acc[mt][nt]);
  }
}

// Fallback K=64 segment with A gathered from fp32 x_r/x_t inline.
template <int MT>
__device__ __forceinline__ void gemm_x(const float* __restrict__ xr,
                                       const float* __restrict__ xt, int t,
                                       const half_t* __restrict__ W,
                                       const int* wrow, int m0, int lane,
                                       floatx4 (&acc)[MT][4]) {
  const int lk = (lane >> 4) * 8;
  const int l15 = lane & 15;
#pragma unroll
  for (int ks = 0; ks < 2; ++ks) {
    const int kb = ks * 32 + lk;
    half8 b[4];
#pragma unroll
    for (int nt = 0; nt < 4; ++nt)
      b[nt] = *(const half8*)(W + (long)(wrow[nt] + l15) * 64 + kb);
    half8 a[MT];
#pragma unroll
    for (int mt = 0; mt < MT; ++mt) {
      const int row = m0 + mt * 16 + l15;
      const long base = (long)row * 512 + t;
#pragma unroll
      for (int j = 0; j < 8; ++j) {
        const int k = kb + j;
        float f = 0.f;
        if (k < 47) f = xr[base * 47 + k];
        else if (k < 49) f = xt[base * 2 + (k - 47)];
        a[mt][j] = (half_t)f;
      }
    }
#pragma unroll
    for (int mt = 0; mt < MT; ++mt)
#pragma unroll
      for (int nt = 0; nt < 4; ++nt)
        acc[mt][nt] = mfma16(a[mt], b[nt], acc[mt][nt]);
  }
}

// LSTM epilogue: acc [MT][4 gates i,f,g,o] at h-cols c0+(lane&15)
template <int MT>
__device__ __forceinline__ void lstm_epi(floatx4 (&acc)[MT][4],
                                         const float* __restrict__ bias,
                                         float* __restrict__ cst,
                                         half_t* __restrict__ hdst, int m0,
                                         int c0, int lane) {
  const int col = c0 + (lane & 15);
  const float bI = bias[col], bF = bias[512 + col], bG = bias[1024 + col],
              bO = bias[1536 + col];
#pragma unroll
  for (int mt = 0; mt < MT; ++mt)
#pragma unroll
    for (int r = 0; r < 4; ++r) {
      const int row = m0 + mt * 16 + ((lane >> 4) << 2) + r;
      const float gi = acc[mt][0][r] + bI;
      const float gf = acc[mt][1][r] + bF;
      const float gg = acc[mt][2][r] + bG;
      const float go = acc[mt][3][r] + bO;
      const int off = row * 512 + col;
      const float cold = cst[off];
      const float cn = fast_sig(gf) * cold + fast_sig(gi) * fast_tanh(gg);
      cst[off] = cn;
      hdst[off] = (half_t)(fast_sig(go) * fast_tanh(cn));
    }
}

// Sense-reversing grid barrier. bar[0]=arrival counter, bar[64]=generation.
// Agent-scope release fence before arrival makes this block's writes visible
// device-wide (cross-XCD); acquire fence after the generation flip invalidates
// stale L1/L2 lines before the next tick's reads.
__device__ __forceinline__ void grid_barrier(unsigned* bar) {
  __syncthreads();
  if (threadIdx.x == 0) {
    __builtin_amdgcn_fence(__ATOMIC_RELEASE, "agent");
    unsigned g = __hip_atomic_load(bar + 64, __ATOMIC_RELAXED,
                                   __HIP_MEMORY_SCOPE_AGENT);
    unsigned a = __hip_atomic_fetch_add(bar, 1u, __ATOMIC_RELAXED,
                                        __HIP_MEMORY_SCOPE_AGENT);
    if (a == NBLK - 1) {
      __hip_atomic_store(bar, 0u, __ATOMIC_RELAXED, __HIP_MEMORY_SCOPE_AGENT);
      __hip_atomic_store(bar + 64, g + 1u, __ATOMIC_RELEASE,
                         __HIP_MEMORY_SCOPE_AGENT);
    } else {
      while (__hip_atomic_load(bar + 64, __ATOMIC_RELAXED,
                               __HIP_MEMORY_SCOPE_AGENT) == g)
        __builtin_amdgcn_s_sleep(4);
    }
    __builtin_amdgcn_fence(__ATOMIC_ACQUIRE, "agent");
  }
  __syncthreads();
}

__global__ __launch_bounds__(256, 2) void adrnn_persist(
    const float* __restrict__ xr, const float* __restrict__ xt,
    const float* __restrict__ b_r0, const float* __restrict__ b_r1,
    const float* __restrict__ b_t0, const float* __restrict__ b_t1,
    const float* __restrict__ brv, const float* __restrict__ btv,
    half_t* __restrict__ w16, float* __restrict__ cbase,
    float* __restrict__ out, unsigned* bar, const half_t* __restrict__ x16,
    int use_x16) {
  const int bid = blockIdx.x;
  const int tid = threadIdx.x;
  const int lane = tid & 63;
  const int w = tid >> 6;
  half_t* H = w16 + H_BASE;
  half_t* RO = w16 + RO_BASE;
#define HBUF(cell, p) (H + (((cell)*2 + (p)) << 16))

  for (int k = 0; k < 517; ++k) {
    const int par = k & 1, pq = par ^ 1;
    if (bid < 128) {
      const int stage = bid >> 5;
      const int cs = bid & 31;
      const int c0 = cs * 16;
      const int sd = (stage == 0) ? 0 : (stage == 1) ? 1 : (stage == 2) ? 3 : 4;
      const int t = k - sd;
      if (t >= 0 && t < 512) {
        int wrow[4] = {c0, 512 + c0, 1024 + c0, 1536 + c0};
        floatx4 acc[2][4] = {};
        const int m0 = w * 32;
        if (stage == 0) {  // r0: X(t) @ r_Wih0^T + hr0(t-1) @ r_Whh0^T
          if (use_x16)
            gemm_h<2, 4, 64>(x16 + t * 8192, 64, w16 + OFF_W0, 64, wrow, m0,
                             lane, acc);
          else
            gemm_x<2>(xr, xt, t, w16 + OFF_W0, wrow, m0, lane, acc);
          gemm_h<2, 4, 512>(HBUF(0, pq), 512, w16 + OFF_W1, 512, wrow, m0,
                            lane, acc);
          lstm_epi<2>(acc, b_r0, cbase + 0 * 65536, HBUF(0, par), m0, c0, lane);
        } else if (stage == 1) {  // r1
          gemm_h<2, 4, 512>(HBUF(0, pq), 512, w16 + OFF_W2, 512, wrow, m0,
                            lane, acc);
          gemm_h<2, 4, 512>(HBUF(1, pq), 512, w16 + OFF_W3, 512, wrow, m0,
                            lane, acc);
          lstm_epi<2>(acc, b_r1, cbase + 1 * 65536, HBUF(1, par), m0, c0, lane);
        } else if (stage == 2) {  // t0: X + r_out16 + ht0 recurrent
          if (use_x16)
            gemm_h<2, 4, 64>(x16 + t * 8192, 64, w16 + OFF_W4, 64, wrow, m0,
                             lane, acc);
          else
            gemm_x<2>(xr, xt, t, w16 + OFF_W4, wrow, m0, lane, acc);
          gemm_h<2, 4, 64>(RO + pq * 8192, 64, w16 + OFF_W5, 64, wrow, m0,
                           lane, acc);
          gemm_h<2, 4, 512>(HBUF(2, pq), 512, w16 + OFF_W6, 512, wrow, m0,
                            lane, acc);
          lstm_epi<2>(acc, b_t0, cbase + 2 * 65536, HBUF(2, par), m0, c0, lane);
        } else {  // t1
          gemm_h<2, 4, 512>(HBUF(2, pq), 512, w16 + OFF_W7, 512, wrow, m0,
                            lane, acc);
          gemm_h<2, 4, 512>(HBUF(3, pq), 512, w16 + OFF_W8, 512, wrow, m0,
                            lane, acc);
          lstm_epi<2>(acc, b_t1, cbase + 3 * 65536, HBUF(3, par), m0, c0, lane);
        }
      }
    } else if (bid < 130) {  // rout: hr1(t) @ Wr^T + br -> d_out + fp16 copy
      const int t = k - 2;
      if (t >= 0 && t < 512) {
        const int rb = bid - 128;
        int wrow[3] = {0, 16, 32};
        floatx4 acc[1][3] = {};
        const int m0 = rb * 64 + w * 16;
        gemm_h<1, 3, 512>(HBUF(1, pq), 512, w16 + OFF_W9, 512, wrow, m0, lane,
                          acc);
#pragma unroll
        for (int nt = 0; nt < 3; ++nt) {
          const int col = nt * 16 + (lane & 15);
#pragma unroll
          for (int r = 0; r < 4; ++r) {
            const int row = m0 + ((lane >> 4) << 2) + r;
            if (col < 47) {
              const float v = acc[0][nt][r] + brv[col];
              out[((long)row * 512 + t) * 47 + col] = v;
              RO[par * 8192 + row * 64 + col] = (half_t)v;
            } else if (col == 47) {
              RO[par * 8192 + row * 64 + col] = (half_t)0.f;
            }
          }
        }
      }
    } else {  // tout: ht1(t) @ Wt^T + bt
      const int t = k - 5;
      if (t >= 0 && t < 512) {
        int wrow[1] = {0};
        floatx4 acc[2][1] = {};
        const int m0 = w * 32;
        gemm_h<2, 1, 512>(HBUF(3, pq), 512, w16 + OFF_W10, 512, wrow, m0, lane,
                          acc);
        const int col = lane & 15;
        if (col < 2) {
#pragma unroll
          for (int mt = 0; mt < 2; ++mt)
#pragma unroll
            for (int r = 0; r < 4; ++r) {
              const int row = m0 + mt * 16 + ((lane >> 4) << 2) + r;
              out[TOUT_BASE + ((long)row * 512 + t) * 2 + col] =
                  acc[mt][0][r] + btv[col];
            }
        }
      }
    }
    grid_barrier(bar);
  }
#undef HBUF
}

// fp32 -> fp16 weight conversion into [n][k] layout with zero padding.
__global__ __launch_bounds__(256) void conv_w(
    const float* __restrict__ rWih0, const float* __restrict__ rWhh0,
    const float* __restrict__ rWih1, const float* __restrict__ rWhh1,
    const float* __restrict__ tWih0, const float* __restrict__ tWhh0,
    const float* __restrict__ tWih1, const float* __restrict__ tWhh1,
    const float* __restrict__ Wr, const float* __restrict__ Wt,
    half_t* __restrict__ w16) {
  const int idx = blockIdx.x * 256 + threadIdx.x;
  if (idx >= W_TOTAL) return;
  float v = 0.f;
  if (idx < OFF_W1) {
    int n = idx >> 6, kk = idx & 63;
    if (kk < 49) v = rWih0[n * 49 + kk];
  } else if (idx < OFF_W2) {
    int r = idx - OFF_W1; v = rWhh0[r];
  } else if (idx < OFF_W3) {
    int r = idx - OFF_W2; v = rWih1[r];
  } else if (idx < OFF_W4) {
    int r = idx - OFF_W3; v = rWhh1[r];
  } else if (idx < OFF_W5) {
    int r = idx - OFF_W4; int n = r >> 6, kk = r & 63;
    if (kk < 49) v = tWih0[n * 96 + kk];
  } else if (idx < OFF_W6) {
    int r = idx - OFF_W5; int n = r >> 6, kk = r & 63;
    if (kk < 47) v = tWih0[n * 96 + 49 + kk];
  } else if (idx < OFF_W7) {
    int r = idx - OFF_W6; v = tWhh0[r];
  } else if (idx < OFF_W8) {
    int r = idx - OFF_W7; v = tWih1[r];
  } else if (idx < OFF_W9) {
    int r = idx - OFF_W8; v = tWhh1[r];
  } else if (idx < OFF_W10) {
    int r = idx - OFF_W9; int n = r >> 9, kk = r & 511;
    if (n < 47) v = Wr[n * 512 + kk];
  } else {
    int r = idx - OFF_W10; int n = r >> 9, kk = r & 511;
    if (n < 2) v = Wt[n * 512 + kk];
  }
  w16[idx] = (half_t)v;
}

// fp32 x_r/x_t -> fp16 [t][128][64] (cols 0..46 = x_r, 47..48 = x_t, rest 0)
__global__ __launch_bounds__(256) void conv_x(const float* __restrict__ xr,
                                              const float* __restrict__ xt,
                                              half_t* __restrict__ x16) {
  const int idx = blockIdx.x * 256 + threadIdx.x;
  if (idx >= 512 * 128 * 64) return;
  const int kk = idx & 63;
  const int row = (idx >> 6) & 127;
  const int t = idx >> 13;
  float v = 0.f;
  if (kk < 47) v = xr[(row * 512 + t) * 47 + kk];
  else if (kk < 49) v = xt[(row * 512 + t) * 2 + (kk - 47)];
  x16[idx] = (half_t)v;
}

extern "C" void kernel_launch(void* const* d_in, const int* in_sizes, int n_in,
                              void* d_out, int out_size, void* d_ws,
                              size_t ws_size, hipStream_t stream) {
  const float* xr = (const float*)d_in[0];
  const float* xt = (const float*)d_in[1];
  const float* rWih0 = (const float*)d_in[2];
  const float* rWhh0 = (const float*)d_in[3];
  const float* r_b0 = (const float*)d_in[4];
  const float* rWih1 = (const float*)d_in[5];
  const float* rWhh1 = (const float*)d_in[6];
  const float* r_b1 = (const float*)d_in[7];
  const float* tWih0 = (const float*)d_in[8];
  const float* tWhh0 = (const float*)d_in[9];
  const float* t_b0 = (const float*)d_in[10];
  const float* tWih1 = (const float*)d_in[11];
  const float* tWhh1 = (const float*)d_in[12];
  const float* t_b1 = (const float*)d_in[13];
  const float* Wr = (const float*)d_in[14];
  const float* br = (const float*)d_in[15];
  const float* Wt = (const float*)d_in[16];
  const float* bt = (const float*)d_in[17];

  half_t* w16 = (half_t*)d_ws;
  float* cbase = (float*)((char*)d_ws + C_BYTE_OFF);
  unsigned* bar = (unsigned*)((char*)d_ws + BAR_BYTE_OFF);
  half_t* x16 = (half_t*)((char*)d_ws + X16_BYTE_OFF);
  float* out = (float*)d_out;
  int use_x16 = (ws_size >= WS_NEED_X16) ? 1 : 0;

  // zero h / ro / c / barrier state every call (deterministic)
  (void)hipMemsetAsync((char*)d_ws + STATE_BYTE_OFF, 0, STATE_BYTES, stream);

  conv_w<<<(W_TOTAL + 255) / 256, 256, 0, stream>>>(
      rWih0, rWhh0, rWih1, rWhh1, tWih0, tWhh0, tWih1, tWhh1, Wr, Wt, w16);
  if (use_x16)
    conv_x<<<(512 * 128 * 64) / 256, 256, 0, stream>>>(xr, xt, x16);

  adrnn_persist<<<NBLK, 256, 0, stream>>>(xr, xt, r_b0, r_b1, t_b0, t_b1, br,
                                          bt, w16, cbase, out, bar, x16,
                                          use_x16);
}

// Round 5
// 14807.335 us; speedup vs baseline: 1.2116x; 1.2116x over previous
//
#include <hip/hip_runtime.h>

// ---------------------------------------------------------------------------
// ADRNN persistent, fence-free ticks.
// 256 blocks x 256 threads (1 block/CU). Stages pipelined across ticks:
//   tick k: r0(t=k) | r1(k-1) | rout(k-2) | t0(k-3) | t1(k-4) | tout(k-5)
// Cross-block data (h, RO) exchanged via RELAXED agent-scope atomics (sc0/sc1,
// LLC-coherent across XCDs) -> NO buffer_wbl2/buffer_inv per tick; weights
// stay L2-resident. Barrier: vmcnt(0) + two-level relaxed atomic counter tree.
// MFMA operands SWAPPED (A=W, B=h): lane owns 4 consecutive h-cols of one
// batch row -> 8B packed h stores, float4 c-state, no shuffles.
// c-state is block-private (persistent blocks) -> plain cached access.
// ---------------------------------------------------------------------------

typedef _Float16 half_t;
typedef _Float16 half8 __attribute__((ext_vector_type(8)));
typedef float floatx4 __attribute__((ext_vector_type(4)));
typedef unsigned long long ull_t;

// half-unit offsets inside d_ws
#define OFF_W0 0        // r_Wih0 padded  [2048][64]
#define OFF_W1 131072   // r_Whh0         [2048][512]
#define OFF_W2 1179648  // r_Wih1         [2048][512]
#define OFF_W3 2228224  // r_Whh1         [2048][512]
#define OFF_W4 3276800  // t_Wih0 cols0-48 padded [2048][64]
#define OFF_W5 3407872  // t_Wih0 cols49-95 padded [2048][64]
#define OFF_W6 3538944  // t_Whh0         [2048][512]
#define OFF_W7 4587520  // t_Wih1         [2048][512]
#define OFF_W8 5636096  // t_Whh1         [2048][512]
#define OFF_W9 6684672  // Wr padded      [48][512]
#define OFF_W10 6709248 // Wt padded      [16][512]
#define W_TOTAL 6717440
#define H_BASE  6717440              // h[4 cells][2 par][128][512] halves
#define RO_BASE 7241728              // rout16[2 par][128][64] halves
#define HALF_TOTAL 7258112
// byte offsets
#define STATE_BYTE_OFF (H_BASE * 2)          // 13434880
#define C_BYTE_OFF (HALF_TOTAL * 2)          // 14516224 (c: 4x[128][512] f32)
#define BAR_BYTE_OFF 15564800                // barrier state (4 KiB)
#define X16_BYTE_OFF (BAR_BYTE_OFF + 4096)   // optional x16 [512][128][64]
#define WS_NEED_X16 ((unsigned long long)X16_BYTE_OFF + 8388608ull)
#define STATE_BYTES (X16_BYTE_OFF - STATE_BYTE_OFF)  // h+ro+c+barrier

#define NBLK 256
#define TOUT_BASE (128 * 512 * 47)

__device__ __forceinline__ floatx4 mfma16(half8 a, half8 b, floatx4 c) {
  return __builtin_amdgcn_mfma_f32_16x16x32_f16(a, b, c, 0, 0, 0);
}

__device__ __forceinline__ float fast_sig(float x) {
  x = fminf(fmaxf(x, -30.f), 30.f);
  float e = __expf(-x);
  return __builtin_amdgcn_rcpf(1.f + e);
}
__device__ __forceinline__ float fast_tanh(float x) {
  x = fminf(fmaxf(x, -15.f), 15.f);
  float e = __expf(-2.f * x);
  return (1.f - e) * __builtin_amdgcn_rcpf(1.f + e);
}

// ---- LLC-coherent (agent-scope relaxed) load/store helpers ----
__device__ __forceinline__ half8 load_b16_coh(const half_t* p) {
  union { ull_t u[2]; half8 v; } x;
  x.u[0] = __hip_atomic_load((const ull_t*)p, __ATOMIC_RELAXED,
                             __HIP_MEMORY_SCOPE_AGENT);
  x.u[1] = __hip_atomic_load(((const ull_t*)p) + 1, __ATOMIC_RELAXED,
                             __HIP_MEMORY_SCOPE_AGENT);
  return x.v;
}
__device__ __forceinline__ void store_h4_coh(half_t* p, half_t h0, half_t h1,
                                             half_t h2, half_t h3) {
  union { ull_t u; _Float16 h[4]; } x;
  x.h[0] = h0; x.h[1] = h1; x.h[2] = h2; x.h[3] = h3;
  __hip_atomic_store((ull_t*)p, x.u, __ATOMIC_RELAXED,
                     __HIP_MEMORY_SCOPE_AGENT);
}

// ---- Swapped-operand GEMM: D[gate_col][batch] = W x h^T ----
// A-frag (W): lane holds m=l15 -> W[(wrow[n]+l15)][kb..kb+7]  (plain, L2)
// B-frag (h): lane holds n=l15 -> h[batch][kb..kb+7]          (COH ? sc1 : plain)
// C/D: lane l -> col(batch)=l15, rows(hcols)=q*4+r  [m89 layout, relabeled]
template <int NT, int K, int LDW, bool COH>
__device__ __forceinline__ void gemm_sw(const half_t* __restrict__ W,
                                        const int* wrow,
                                        const half_t* __restrict__ hb,
                                        int lk, int l15, floatx4 (&acc)[NT]) {
#pragma unroll 4
  for (int ks = 0; ks < K / 32; ++ks) {
    const int kb = ks * 32 + lk;
    half8 b;
    if constexpr (COH) b = load_b16_coh(hb + kb);
    else b = *(const half8*)(hb + kb);
#pragma unroll
    for (int n = 0; n < NT; ++n) {
      half8 a = *(const half8*)(W + (long)(wrow[n] + l15) * LDW + kb);
      acc[n] = mfma16(a, b, acc[n]);
    }
  }
}

// Fallback X-gemm (no x16 buffer): B built from fp32 x_r/x_t gathers.
__device__ __forceinline__ void gemm_xf(const float* __restrict__ xr,
                                        const float* __restrict__ xt, int t,
                                        int batch, const half_t* __restrict__ W,
                                        const int* wrow, int lk, int l15,
                                        floatx4 (&acc)[4]) {
#pragma unroll
  for (int ks = 0; ks < 2; ++ks) {
    const int kb = ks * 32 + lk;
    half8 b;
    const long base = (long)batch * 512 + t;
#pragma unroll
    for (int j = 0; j < 8; ++j) {
      const int kk = kb + j;
      float f = 0.f;
      if (kk < 47) f = xr[base * 47 + kk];
      else if (kk < 49) f = xt[base * 2 + (kk - 47)];
      b[j] = (half_t)f;
    }
#pragma unroll
    for (int n = 0; n < 4; ++n) {
      half8 a = *(const half8*)(W + (long)(wrow[n] + l15) * 64 + kb);
      acc[n] = mfma16(a, b, acc[n]);
    }
  }
}

// LSTM epilogue (swapped layout): lane owns batch row `batch`, h-cols
// hcol0..hcol0+3. acc[4] = gates i,f,g,o.
__device__ __forceinline__ void lstm_epi_sw(floatx4 (&acc)[4],
                                            const float* __restrict__ bias,
                                            float* __restrict__ cst,
                                            half_t* __restrict__ hdst,
                                            int batch, int hcol0) {
  const floatx4 bI = *(const floatx4*)(bias + hcol0);
  const floatx4 bF = *(const floatx4*)(bias + 512 + hcol0);
  const floatx4 bG = *(const floatx4*)(bias + 1024 + hcol0);
  const floatx4 bO = *(const floatx4*)(bias + 1536 + hcol0);
  const int off = batch * 512 + hcol0;
  floatx4 cold = *(floatx4*)(cst + off);
  floatx4 cn;
  half_t hn[4];
#pragma unroll
  for (int r = 0; r < 4; ++r) {
    const float gi = acc[0][r] + bI[r];
    const float gf = acc[1][r] + bF[r];
    const float gg = acc[2][r] + bG[r];
    const float go = acc[3][r] + bO[r];
    cn[r] = fast_sig(gf) * cold[r] + fast_sig(gi) * fast_tanh(gg);
    hn[r] = (half_t)(fast_sig(go) * fast_tanh(cn[r]));
  }
  *(floatx4*)(cst + off) = cn;
  store_h4_coh(hdst + off, hn[0], hn[1], hn[2], hn[3]);
}

__global__ __launch_bounds__(256) void adrnn_persist(
    const float* __restrict__ xr, const float* __restrict__ xt,
    const float* __restrict__ b_r0, const float* __restrict__ b_r1,
    const float* __restrict__ b_t0, const float* __restrict__ b_t1,
    const float* __restrict__ brv, const float* __restrict__ btv,
    half_t* __restrict__ w16, float* __restrict__ cbase,
    float* __restrict__ out, unsigned* bar, const half_t* __restrict__ x16,
    int use_x16) {
  const int bid = blockIdx.x;
  const int tid = threadIdx.x;
  const int lane = tid & 63;
  const int w = tid >> 6;
  const int l15 = lane & 15;
  const int q = lane >> 4;
  const int lk = q * 8;
  half_t* H = w16 + H_BASE;
  half_t* RO = w16 + RO_BASE;
#define HB(cell, p) (H + (((cell)*2 + (p)) << 16))

  const int stage = bid >> 6;       // 0..3
  const int sub = bid & 63;
  const int cs = sub >> 1;          // 0..31 -> 16 h-cols each
  const int bh = sub & 1;           // batch half
  const int c0 = cs * 16;
  const int batch = bh * 64 + w * 16 + l15;
  const int hboff = batch * 512;
  const int hcol0 = c0 + q * 4;
  const int sd = (stage == 0) ? 0 : (stage == 1) ? 1 : (stage == 2) ? 3 : 4;
  int wrow[4] = {c0, 512 + c0, 1024 + c0, 1536 + c0};
  const int flat = sub * 4 + w;     // r0 extra-tile id (0..255)

  for (int k = 0; k < 517; ++k) {
    const int par = k & 1, pq = par ^ 1;
    const int t = k - sd;
    if (t >= 0 && t < 512) {
      floatx4 acc[4] = {};
      if (stage == 0) {        // r0: X @ Wih0^T + hr0 @ Whh0^T
        if (use_x16)
          gemm_sw<4, 64, 64, false>(w16 + OFF_W0, wrow, x16 + t * 8192 + batch * 64,
                                    lk, l15, acc);
        else
          gemm_xf(xr, xt, t, batch, w16 + OFF_W0, wrow, lk, l15, acc);
        gemm_sw<4, 512, 512, true>(w16 + OFF_W1, wrow, HB(0, pq) + hboff, lk, l15, acc);
        lstm_epi_sw(acc, b_r0, cbase + 0 * 65536, HB(0, par), batch, hcol0);
      } else if (stage == 1) { // r1
        gemm_sw<4, 512, 512, true>(w16 + OFF_W2, wrow, HB(0, pq) + hboff, lk, l15, acc);
        gemm_sw<4, 512, 512, true>(w16 + OFF_W3, wrow, HB(1, pq) + hboff, lk, l15, acc);
        lstm_epi_sw(acc, b_r1, cbase + 1 * 65536, HB(1, par), batch, hcol0);
      } else if (stage == 2) { // t0: X + RO + ht0
        if (use_x16)
          gemm_sw<4, 64, 64, false>(w16 + OFF_W4, wrow, x16 + t * 8192 + batch * 64,
                                    lk, l15, acc);
        else
          gemm_xf(xr, xt, t, batch, w16 + OFF_W4, wrow, lk, l15, acc);
        gemm_sw<4, 64, 64, true>(w16 + OFF_W5, wrow, RO + pq * 8192 + batch * 64,
                                 lk, l15, acc);
        gemm_sw<4, 512, 512, true>(w16 + OFF_W6, wrow, HB(2, pq) + hboff, lk, l15, acc);
        lstm_epi_sw(acc, b_t0, cbase + 2 * 65536, HB(2, par), batch, hcol0);
      } else {                 // t1
        gemm_sw<4, 512, 512, true>(w16 + OFF_W7, wrow, HB(2, pq) + hboff, lk, l15, acc);
        gemm_sw<4, 512, 512, true>(w16 + OFF_W8, wrow, HB(3, pq) + hboff, lk, l15, acc);
        lstm_epi_sw(acc, b_t1, cbase + 3 * 65536, HB(3, par), batch, hcol0);
      }
    }
    // rout/tout: folded into 32 spare r0 waves (r0 is the lightest stage)
    if (stage == 0 && flat < 32) {
      if (flat < 24) {  // rout tile: n-tile (0..2) x batch-tile (0..7)
        const int tr = k - 2;
        if (tr >= 0 && tr < 512) {
          const int n = flat >> 3, bt = flat & 7;
          const int rb = bt * 16 + l15;
          int wr1[1] = {n * 16};
          floatx4 accr[1] = {};
          gemm_sw<1, 512, 512, true>(w16 + OFF_W9, wr1, HB(1, pq) + rb * 512,
                                     lk, l15, accr);
          const int wc0 = n * 16 + q * 4;
          half_t ro4[4];
#pragma unroll
          for (int r = 0; r < 4; ++r) {
            const int wc = wc0 + r;
            float v = 0.f;
            if (wc < 47) {
              v = accr[0][r] + brv[wc];
              out[((long)rb * 512 + tr) * 47 + wc] = v;
            }
            ro4[r] = (half_t)v;
          }
          store_h4_coh(RO + par * 8192 + rb * 64 + wc0, ro4[0], ro4[1], ro4[2], ro4[3]);
        }
      } else {          // tout tile: batch-tile (0..7)
        const int tt = k - 5;
        if (tt >= 0 && tt < 512) {
          const int bt = flat - 24;
          const int rb = bt * 16 + l15;
          int wt1[1] = {0};
          floatx4 accw[1] = {};
          gemm_sw<1, 512, 512, true>(w16 + OFF_W10, wt1, HB(3, pq) + rb * 512,
                                     lk, l15, accw);
          if (q == 0) {
#pragma unroll
            for (int r = 0; r < 2; ++r)
              out[TOUT_BASE + ((long)rb * 512 + tt) * 2 + r] = accw[0][r] + btv[r];
          }
        }
      }
    }
    // ---- fence-free grid barrier ----
    // All cross-block traffic was sc1 (LLC); vmcnt(0) => visible device-wide.
    asm volatile("s_waitcnt vmcnt(0)" ::: "memory");
    __syncthreads();
    if (tid == 0) {
      unsigned* genp = bar + 32;
      unsigned* l2c = bar;
      unsigned* grp = bar + 64 + ((bid >> 5) * 32);
      const unsigned g_old = __hip_atomic_load(genp, __ATOMIC_RELAXED,
                                               __HIP_MEMORY_SCOPE_AGENT);
      bool flip = false;
      unsigned a = __hip_atomic_fetch_add(grp, 1u, __ATOMIC_RELAXED,
                                          __HIP_MEMORY_SCOPE_AGENT);
      if (a == 31u) {
        unsigned a2 = __hip_atomic_fetch_add(l2c, 1u, __ATOMIC_RELAXED,
                                             __HIP_MEMORY_SCOPE_AGENT);
        if (a2 == 7u) flip = true;
      }
      if (flip) {
        __hip_atomic_store(l2c, 0u, __ATOMIC_RELAXED, __HIP_MEMORY_SCOPE_AGENT);
#pragma unroll
        for (int g2 = 0; g2 < 8; ++g2)
          __hip_atomic_store(bar + 64 + g2 * 32, 0u, __ATOMIC_RELAXED,
                             __HIP_MEMORY_SCOPE_AGENT);
        asm volatile("s_waitcnt vmcnt(0)" ::: "memory");  // resets land first
        __hip_atomic_store(genp, g_old + 1u, __ATOMIC_RELAXED,
                           __HIP_MEMORY_SCOPE_AGENT);
      } else {
        while (__hip_atomic_load(genp, __ATOMIC_RELAXED,
                                 __HIP_MEMORY_SCOPE_AGENT) == g_old)
          __builtin_amdgcn_s_sleep(2);
      }
    }
    __syncthreads();
    asm volatile("" ::: "memory");  // no compiler reordering across the tick
  }
#undef HB
}

// fp32 -> fp16 weight conversion into [n][k] layout with zero padding.
__global__ __launch_bounds__(256) void conv_w(
    const float* __restrict__ rWih0, const float* __restrict__ rWhh0,
    const float* __restrict__ rWih1, const float* __restrict__ rWhh1,
    const float* __restrict__ tWih0, const float* __restrict__ tWhh0,
    const float* __restrict__ tWih1, const float* __restrict__ tWhh1,
    const float* __restrict__ Wr, const float* __restrict__ Wt,
    half_t* __restrict__ w16) {
  const int idx = blockIdx.x * 256 + threadIdx.x;
  if (idx >= W_TOTAL) return;
  float v = 0.f;
  if (idx < OFF_W1) {
    int n = idx >> 6, kk = idx & 63;
    if (kk < 49) v = rWih0[n * 49 + kk];
  } else if (idx < OFF_W2) {
    int r = idx - OFF_W1; v = rWhh0[r];
  } else if (idx < OFF_W3) {
    int r = idx - OFF_W2; v = rWih1[r];
  } else if (idx < OFF_W4) {
    int r = idx - OFF_W3; v = rWhh1[r];
  } else if (idx < OFF_W5) {
    int r = idx - OFF_W4; int n = r >> 6, kk = r & 63;
    if (kk < 49) v = tWih0[n * 96 + kk];
  } else if (idx < OFF_W6) {
    int r = idx - OFF_W5; int n = r >> 6, kk = r & 63;
    if (kk < 47) v = tWih0[n * 96 + 49 + kk];
  } else if (idx < OFF_W7) {
    int r = idx - OFF_W6; v = tWhh0[r];
  } else if (idx < OFF_W8) {
    int r = idx - OFF_W7; v = tWih1[r];
  } else if (idx < OFF_W9) {
    int r = idx - OFF_W8; v = tWhh1[r];
  } else if (idx < OFF_W10) {
    int r = idx - OFF_W9; int n = r >> 9, kk = r & 511;
    if (n < 47) v = Wr[n * 512 + kk];
  } else {
    int r = idx - OFF_W10; int n = r >> 9, kk = r & 511;
    if (n < 2) v = Wt[n * 512 + kk];
  }
  w16[idx] = (half_t)v;
}

// fp32 x_r/x_t -> fp16 [t][128][64] (cols 0..46 = x_r, 47..48 = x_t, rest 0)
__global__ __launch_bounds__(256) void conv_x(const float* __restrict__ xr,
                                              const float* __restrict__ xt,
                                              half_t* __restrict__ x16) {
  const int idx = blockIdx.x * 256 + threadIdx.x;
  if (idx >= 512 * 128 * 64) return;
  const int kk = idx & 63;
  const int row = (idx >> 6) & 127;
  const int t = idx >> 13;
  float v = 0.f;
  if (kk < 47) v = xr[(row * 512 + t) * 47 + kk];
  else if (kk < 49) v = xt[(row * 512 + t) * 2 + (kk - 47)];
  x16[idx] = (half_t)v;
}

extern "C" void kernel_launch(void* const* d_in, const int* in_sizes, int n_in,
                              void* d_out, int out_size, void* d_ws,
                              size_t ws_size, hipStream_t stream) {
  const float* xr = (const float*)d_in[0];
  const float* xt = (const float*)d_in[1];
  const float* rWih0 = (const float*)d_in[2];
  const float* rWhh0 = (const float*)d_in[3];
  const float* r_b0 = (const float*)d_in[4];
  const float* rWih1 = (const float*)d_in[5];
  const float* rWhh1 = (const float*)d_in[6];
  const float* r_b1 = (const float*)d_in[7];
  const float* tWih0 = (const float*)d_in[8];
  const float* tWhh0 = (const float*)d_in[9];
  const float* t_b0 = (const float*)d_in[10];
  const float* tWih1 = (const float*)d_in[11];
  const float* tWhh1 = (const float*)d_in[12];
  const float* t_b1 = (const float*)d_in[13];
  const float* Wr = (const float*)d_in[14];
  const float* br = (const float*)d_in[15];
  const float* Wt = (const float*)d_in[16];
  const float* bt = (const float*)d_in[17];

  half_t* w16 = (half_t*)d_ws;
  float* cbase = (float*)((char*)d_ws + C_BYTE_OFF);
  unsigned* bar = (unsigned*)((char*)d_ws + BAR_BYTE_OFF);
  half_t* x16 = (half_t*)((char*)d_ws + X16_BYTE_OFF);
  float* out = (float*)d_out;
  int use_x16 = (ws_size >= WS_NEED_X16) ? 1 : 0;

  // zero h / ro / c / barrier state every call (deterministic)
  (void)hipMemsetAsync((char*)d_ws + STATE_BYTE_OFF, 0, STATE_BYTES, stream);

  conv_w<<<(W_TOTAL + 255) / 256, 256, 0, stream>>>(
      rWih0, rWhh0, rWih1, rWhh1, tWih0, tWhh0, tWih1, tWhh1, Wr, Wt, w16);
  if (use_x16)
    conv_x<<<(512 * 128 * 64) / 256, 256, 0, stream>>>(xr, xt, x16);

  adrnn_persist<<<NBLK, 256, 0, stream>>>(xr, xt, r_b0, r_b1, t_b0, t_b1, br,
                                          bt, w16, cbase, out, bar, x16,
                                          use_x16);
}

// Round 6
// 10860.841 us; speedup vs baseline: 1.6518x; 1.3634x over previous
//
#include <hip/hip_runtime.h>

// ---------------------------------------------------------------------------
// ADRNN persistent, latency-batched coherent loads + XCD-pinned stages.
// 256 blocks x 256 threads (1 block/CU). Stages pipelined across ticks:
//   tick k: r0(t=k) | r1(k-1) | rout(k-2) | t0(k-3) | t1(k-4) | tout(k-5)
// Cross-block h/RO reads: inline-asm global_load_dwordx4 sc0 sc1 (LLC-coherent,
// issued in ONE burst per tick -> single latency window), h stores: 8B relaxed
// agent atomics. Weights fp16 [n][k], L2-resident per-XCD via bid remap:
//   bid = csLo*16 + bh*8 + stage*2 + csHi  (stage s -> XCDs 2s,2s+1,
//   each XCD holds only half the stage's weight rows ~2.2MB < 4MB L2).
// Barrier: per-XCD arrival counters + per-XCD generation broadcast lines,
// all relaxed atomics, vmcnt(0) drain before arrival. No L2 wb/inv anywhere.
// ---------------------------------------------------------------------------

typedef _Float16 half_t;
typedef _Float16 half8 __attribute__((ext_vector_type(8)));
typedef float floatx4 __attribute__((ext_vector_type(4)));
typedef unsigned long long ull_t;

// half-unit offsets inside d_ws
#define OFF_W0 0        // r_Wih0 padded  [2048][64]
#define OFF_W1 131072   // r_Whh0         [2048][512]
#define OFF_W2 1179648  // r_Wih1         [2048][512]
#define OFF_W3 2228224  // r_Whh1         [2048][512]
#define OFF_W4 3276800  // t_Wih0 cols0-48 padded [2048][64]
#define OFF_W5 3407872  // t_Wih0 cols49-95 padded [2048][64]
#define OFF_W6 3538944  // t_Whh0         [2048][512]
#define OFF_W7 4587520  // t_Wih1         [2048][512]
#define OFF_W8 5636096  // t_Whh1         [2048][512]
#define OFF_W9 6684672  // Wr padded      [48][512]
#define OFF_W10 6709248 // Wt padded      [16][512]
#define W_TOTAL 6717440
#define H_BASE  6717440              // h[4 cells][2 par][128][512] halves
#define RO_BASE 7241728              // rout16[2 par][128][64] halves
#define HALF_TOTAL 7258112
// byte offsets
#define STATE_BYTE_OFF (H_BASE * 2)          // 13434880
#define C_BYTE_OFF (HALF_TOTAL * 2)          // 14516224 (c: 4x[128][512] f32)
#define BAR_BYTE_OFF 15564800                // barrier state (4 KiB)
#define X16_BYTE_OFF (BAR_BYTE_OFF + 4096)   // optional x16 [512][128][64]
#define WS_NEED_X16 ((unsigned long long)X16_BYTE_OFF + 8388608ull)
#define STATE_BYTES (X16_BYTE_OFF - STATE_BYTE_OFF)  // h+ro+c+barrier

#define NBLK 256
#define TOUT_BASE (128 * 512 * 47)

__device__ __forceinline__ floatx4 mfma16(half8 a, half8 b, floatx4 c) {
  return __builtin_amdgcn_mfma_f32_16x16x32_f16(a, b, c, 0, 0, 0);
}

__device__ __forceinline__ float fast_sig(float x) {
  x = fminf(fmaxf(x, -30.f), 30.f);
  float e = __expf(-x);
  return __builtin_amdgcn_rcpf(1.f + e);
}
__device__ __forceinline__ float fast_tanh(float x) {
  x = fminf(fmaxf(x, -15.f), 15.f);
  float e = __expf(-2.f * x);
  return (1.f - e) * __builtin_amdgcn_rcpf(1.f + e);
}

// Issue N coherent 16B loads (read-through L1/L2 -> LLC) in one burst.
// p = per-lane base (already includes the lane's k offset); frag ks at +64B*ks.
template <int N>
__device__ __forceinline__ void coh_stage(half8 (&bb)[N], const half_t* p) {
#pragma unroll
  for (int ks = 0; ks < N; ++ks)
    asm volatile("global_load_dwordx4 %0, %1, off sc0 sc1"
                 : "=v"(bb[ks])
                 : "v"(p + ks * 32));
}
// Single drain for the whole burst. sched_barrier keeps consumers below
// (rule: compiler may otherwise hoist register-only MFMAs past the waitcnt).
__device__ __forceinline__ void drain_vm() {
  asm volatile("s_waitcnt vmcnt(0)" ::: "memory");
  __builtin_amdgcn_sched_barrier(0);
}

__device__ __forceinline__ void store_h4_coh(half_t* p, half_t h0, half_t h1,
                                             half_t h2, half_t h3) {
  union { ull_t u; _Float16 h[4]; } x;
  x.h[0] = h0; x.h[1] = h1; x.h[2] = h2; x.h[3] = h3;
  __hip_atomic_store((ull_t*)p, x.u, __ATOMIC_RELAXED,
                     __HIP_MEMORY_SCOPE_AGENT);
}

// MFMA over staged B-fragments; W streamed with plain (L2-cached) loads.
// C/D: lane l -> col(batch)=l15, rows(gate hcols)=q*4+r.
template <int NT, int NSEG, int LDW>
__device__ __forceinline__ void gemm_staged(const half_t* __restrict__ W,
                                            const int* wrow,
                                            const half8 (&bb)[NSEG], int lk,
                                            int l15, floatx4 (&acc)[NT]) {
#pragma unroll
  for (int ks = 0; ks < NSEG; ++ks) {
    const int kb = ks * 32 + lk;
#pragma unroll
    for (int n = 0; n < NT; ++n) {
      half8 a = *(const half8*)(W + (long)(wrow[n] + l15) * LDW + kb);
      acc[n] = mfma16(a, bb[ks], acc[n]);
    }
  }
}

// K=64 gemm with plain (x16, L2) B loads.
__device__ __forceinline__ void gemm_plain2(const half_t* __restrict__ W,
                                            const int* wrow,
                                            const half_t* __restrict__ xb,
                                            int lk, int l15, floatx4 (&acc)[4]) {
#pragma unroll
  for (int ks = 0; ks < 2; ++ks) {
    const int kb = ks * 32 + lk;
    half8 b = *(const half8*)(xb + kb);
#pragma unroll
    for (int n = 0; n < 4; ++n) {
      half8 a = *(const half8*)(W + (long)(wrow[n] + l15) * 64 + kb);
      acc[n] = mfma16(a, b, acc[n]);
    }
  }
}

// Fallback X-gemm (no x16 buffer): B built from fp32 x_r/x_t gathers.
__device__ __forceinline__ void gemm_xf(const float* __restrict__ xr,
                                        const float* __restrict__ xt, int t,
                                        int batch, const half_t* __restrict__ W,
                                        const int* wrow, int lk, int l15,
                                        floatx4 (&acc)[4]) {
#pragma unroll
  for (int ks = 0; ks < 2; ++ks) {
    const int kb = ks * 32 + lk;
    half8 b;
    const long base = (long)batch * 512 + t;
#pragma unroll
    for (int j = 0; j < 8; ++j) {
      const int kk = kb + j;
      float f = 0.f;
      if (kk < 47) f = xr[base * 47 + kk];
      else if (kk < 49) f = xt[base * 2 + (kk - 47)];
      b[j] = (half_t)f;
    }
#pragma unroll
    for (int n = 0; n < 4; ++n) {
      half8 a = *(const half8*)(W + (long)(wrow[n] + l15) * 64 + kb);
      acc[n] = mfma16(a, b, acc[n]);
    }
  }
}

// LSTM epilogue: lane owns batch row `batch`, h-cols hcol0..hcol0+3.
__device__ __forceinline__ void lstm_epi_sw(floatx4 (&acc)[4],
                                            const float* __restrict__ bias,
                                            float* __restrict__ cst,
                                            half_t* __restrict__ hdst,
                                            int batch, int hcol0) {
  const floatx4 bI = *(const floatx4*)(bias + hcol0);
  const floatx4 bF = *(const floatx4*)(bias + 512 + hcol0);
  const floatx4 bG = *(const floatx4*)(bias + 1024 + hcol0);
  const floatx4 bO = *(const floatx4*)(bias + 1536 + hcol0);
  const int off = batch * 512 + hcol0;
  floatx4 cold = *(floatx4*)(cst + off);
  floatx4 cn;
  half_t hn[4];
#pragma unroll
  for (int r = 0; r < 4; ++r) {
    const float gi = acc[0][r] + bI[r];
    const float gf = acc[1][r] + bF[r];
    const float gg = acc[2][r] + bG[r];
    const float go = acc[3][r] + bO[r];
    cn[r] = fast_sig(gf) * cold[r] + fast_sig(gi) * fast_tanh(gg);
    hn[r] = (half_t)(fast_sig(go) * fast_tanh(cn[r]));
  }
  *(floatx4*)(cst + off) = cn;
  store_h4_coh(hdst + off, hn[0], hn[1], hn[2], hn[3]);
}

__global__ __launch_bounds__(256, 1) void adrnn_persist(
    const float* __restrict__ xr, const float* __restrict__ xt,
    const float* __restrict__ b_r0, const float* __restrict__ b_r1,
    const float* __restrict__ b_t0, const float* __restrict__ b_t1,
    const float* __restrict__ brv, const float* __restrict__ btv,
    half_t* __restrict__ w16, float* __restrict__ cbase,
    float* __restrict__ out, unsigned* bar, const half_t* __restrict__ x16,
    int use_x16) {
  const int bid = blockIdx.x;
  const int tid = threadIdx.x;
  const int lane = tid & 63;
  const int w = tid >> 6;
  const int l15 = lane & 15;
  const int q = lane >> 4;
  const int lk = q * 8;
  half_t* H = w16 + H_BASE;
  half_t* RO = w16 + RO_BASE;
#define HB(cell, p) (H + (((cell)*2 + (p)) << 16))

  // XCD-pinned decode: bid = csLo*16 + bh*8 + stage*2 + csHi
  const int stage = (bid & 7) >> 1;  // 0..3 -> XCDs {2s,2s+1}
  const int csHi = bid & 1;
  const int bh = (bid >> 3) & 1;
  const int csLo = bid >> 4;         // 0..15
  const int cs = csHi * 16 + csLo;   // 0..31
  const int sub = cs * 2 + bh;       // 0..63
  const int c0 = cs * 16;
  const int batch = bh * 64 + w * 16 + l15;
  const int hboff = batch * 512;
  const int hcol0 = c0 + q * 4;
  const int sd = (stage == 0) ? 0 : (stage == 1) ? 1 : (stage == 2) ? 3 : 4;
  int wrow[4] = {c0, 512 + c0, 1024 + c0, 1536 + c0};
  const int flat = sub * 4 + w;      // stage-0 spare-tile id

  unsigned* grp = bar + (bid & 7) * 16;        // per-XCD arrival counter
  unsigned* l2c = bar + 128;                   // top-level counter
  unsigned* genp = bar + 160 + (bid & 7) * 16; // per-XCD generation line

  for (int k = 0; k < 517; ++k) {
    const int par = k & 1, pq = par ^ 1;
    const int t = k - sd;
    if (t >= 0 && t < 512) {
      floatx4 acc[4] = {};
      if (stage == 0) {        // r0: X @ Wih0^T + hr0 @ Whh0^T
        half8 b0[16];
        coh_stage<16>(b0, HB(0, pq) + hboff + lk);
        drain_vm();
        if (use_x16)
          gemm_plain2(w16 + OFF_W0, wrow, x16 + t * 8192 + batch * 64, lk, l15, acc);
        else
          gemm_xf(xr, xt, t, batch, w16 + OFF_W0, wrow, lk, l15, acc);
        gemm_staged<4, 16, 512>(w16 + OFF_W1, wrow, b0, lk, l15, acc);
        lstm_epi_sw(acc, b_r0, cbase + 0 * 65536, HB(0, par), batch, hcol0);
      } else if (stage == 1) { // r1
        half8 b0[16], b1[16];
        coh_stage<16>(b0, HB(0, pq) + hboff + lk);
        coh_stage<16>(b1, HB(1, pq) + hboff + lk);
        drain_vm();
        gemm_staged<4, 16, 512>(w16 + OFF_W2, wrow, b0, lk, l15, acc);
        gemm_staged<4, 16, 512>(w16 + OFF_W3, wrow, b1, lk, l15, acc);
        lstm_epi_sw(acc, b_r1, cbase + 1 * 65536, HB(1, par), batch, hcol0);
      } else if (stage == 2) { // t0: X + RO + ht0
        half8 bro[2], b2[16];
        coh_stage<2>(bro, RO + pq * 8192 + batch * 64 + lk);
        coh_stage<16>(b2, HB(2, pq) + hboff + lk);
        drain_vm();
        if (use_x16)
          gemm_plain2(w16 + OFF_W4, wrow, x16 + t * 8192 + batch * 64, lk, l15, acc);
        else
          gemm_xf(xr, xt, t, batch, w16 + OFF_W4, wrow, lk, l15, acc);
        gemm_staged<4, 2, 64>(w16 + OFF_W5, wrow, bro, lk, l15, acc);
        gemm_staged<4, 16, 512>(w16 + OFF_W6, wrow, b2, lk, l15, acc);
        lstm_epi_sw(acc, b_t0, cbase + 2 * 65536, HB(2, par), batch, hcol0);
      } else {                 // t1
        half8 b0[16], b1[16];
        coh_stage<16>(b0, HB(2, pq) + hboff + lk);
        coh_stage<16>(b1, HB(3, pq) + hboff + lk);
        drain_vm();
        gemm_staged<4, 16, 512>(w16 + OFF_W7, wrow, b0, lk, l15, acc);
        gemm_staged<4, 16, 512>(w16 + OFF_W8, wrow, b1, lk, l15, acc);
        lstm_epi_sw(acc, b_t1, cbase + 3 * 65536, HB(3, par), batch, hcol0);
      }
    }
    // rout/tout folded into stage-0 spare waves (blocks with sub < 8)
    if (stage == 0 && flat < 32) {
      if (flat < 24) {  // rout: n-tile (0..2) x batch-tile (0..7)
        const int tr = k - 2;
        if (tr >= 0 && tr < 512) {
          const int n = flat >> 3, btl = flat & 7;
          const int rb = btl * 16 + l15;
          half8 bs[16];
          coh_stage<16>(bs, HB(1, pq) + rb * 512 + lk);
          drain_vm();
          int wr1[1] = {n * 16};
          floatx4 accr[1] = {};
          gemm_staged<1, 16, 512>(w16 + OFF_W9, wr1, bs, lk, l15, accr);
          const int wc0 = n * 16 + q * 4;
          half_t ro4[4];
#pragma unroll
          for (int r = 0; r < 4; ++r) {
            const int wc = wc0 + r;
            float v = 0.f;
            if (wc < 47) {
              v = accr[0][r] + brv[wc];
              out[((long)rb * 512 + tr) * 47 + wc] = v;
            }
            ro4[r] = (half_t)v;
          }
          store_h4_coh(RO + par * 8192 + rb * 64 + wc0, ro4[0], ro4[1], ro4[2], ro4[3]);
        }
      } else {          // tout: batch-tile (0..7)
        const int tt = k - 5;
        if (tt >= 0 && tt < 512) {
          const int btl = flat - 24;
          const int rb = btl * 16 + l15;
          half8 bs[16];
          coh_stage<16>(bs, HB(3, pq) + rb * 512 + lk);
          drain_vm();
          int wt1[1] = {0};
          floatx4 accw[1] = {};
          gemm_staged<1, 16, 512>(w16 + OFF_W10, wt1, bs, lk, l15, accw);
          if (q == 0) {
#pragma unroll
            for (int r = 0; r < 2; ++r)
              out[TOUT_BASE + ((long)rb * 512 + tt) * 2 + r] = accw[0][r] + btv[r];
          }
        }
      }
    }
    // ---- grid barrier (all relaxed; sc traffic already at LLC) ----
    asm volatile("s_waitcnt vmcnt(0)" ::: "memory");
    __syncthreads();
    if (tid == 0) {
      const unsigned g_old = __hip_atomic_load(genp, __ATOMIC_RELAXED,
                                               __HIP_MEMORY_SCOPE_AGENT);
      bool flip = false;
      unsigned a = __hip_atomic_fetch_add(grp, 1u, __ATOMIC_RELAXED,
                                          __HIP_MEMORY_SCOPE_AGENT);
      if (a == 31u) {
        unsigned a2 = __hip_atomic_fetch_add(l2c, 1u, __ATOMIC_RELAXED,
                                             __HIP_MEMORY_SCOPE_AGENT);
        if (a2 == 7u) flip = true;
      }
      if (flip) {
        __hip_atomic_store(l2c, 0u, __ATOMIC_RELAXED, __HIP_MEMORY_SCOPE_AGENT);
#pragma unroll
        for (int g2 = 0; g2 < 8; ++g2)
          __hip_atomic_store(bar + g2 * 16, 0u, __ATOMIC_RELAXED,
                             __HIP_MEMORY_SCOPE_AGENT);
        asm volatile("s_waitcnt vmcnt(0)" ::: "memory");  // resets land first
#pragma unroll
        for (int g2 = 0; g2 < 8; ++g2)
          __hip_atomic_store(bar + 160 + g2 * 16, g_old + 1u, __ATOMIC_RELAXED,
                             __HIP_MEMORY_SCOPE_AGENT);
      } else {
        while (__hip_atomic_load(genp, __ATOMIC_RELAXED,
                                 __HIP_MEMORY_SCOPE_AGENT) == g_old)
          __builtin_amdgcn_s_sleep(2);
      }
    }
    __syncthreads();
    asm volatile("" ::: "memory");  // no compiler reordering across the tick
  }
#undef HB
}

// fp32 -> fp16 weight conversion into [n][k] layout with zero padding.
__global__ __launch_bounds__(256) void conv_w(
    const float* __restrict__ rWih0, const float* __restrict__ rWhh0,
    const float* __restrict__ rWih1, const float* __restrict__ rWhh1,
    const float* __restrict__ tWih0, const float* __restrict__ tWhh0,
    const float* __restrict__ tWih1, const float* __restrict__ tWhh1,
    const float* __restrict__ Wr, const float* __restrict__ Wt,
    half_t* __restrict__ w16) {
  const int idx = blockIdx.x * 256 + threadIdx.x;
  if (idx >= W_TOTAL) return;
  float v = 0.f;
  if (idx < OFF_W1) {
    int n = idx >> 6, kk = idx & 63;
    if (kk < 49) v = rWih0[n * 49 + kk];
  } else if (idx < OFF_W2) {
    int r = idx - OFF_W1; v = rWhh0[r];
  } else if (idx < OFF_W3) {
    int r = idx - OFF_W2; v = rWih1[r];
  } else if (idx < OFF_W4) {
    int r = idx - OFF_W3; v = rWhh1[r];
  } else if (idx < OFF_W5) {
    int r = idx - OFF_W4; int n = r >> 6, kk = r & 63;
    if (kk < 49) v = tWih0[n * 96 + kk];
  } else if (idx < OFF_W6) {
    int r = idx - OFF_W5; int n = r >> 6, kk = r & 63;
    if (kk < 47) v = tWih0[n * 96 + 49 + kk];
  } else if (idx < OFF_W7) {
    int r = idx - OFF_W6; v = tWhh0[r];
  } else if (idx < OFF_W8) {
    int r = idx - OFF_W7; v = tWih1[r];
  } else if (idx < OFF_W9) {
    int r = idx - OFF_W8; v = tWhh1[r];
  } else if (idx < OFF_W10) {
    int r = idx - OFF_W9; int n = r >> 9, kk = r & 511;
    if (n < 47) v = Wr[n * 512 + kk];
  } else {
    int r = idx - OFF_W10; int n = r >> 9, kk = r & 511;
    if (n < 2) v = Wt[n * 512 + kk];
  }
  w16[idx] = (half_t)v;
}

// fp32 x_r/x_t -> fp16 [t][128][64] (cols 0..46 = x_r, 47..48 = x_t, rest 0)
__global__ __launch_bounds__(256) void conv_x(const float* __restrict__ xr,
                                              const float* __restrict__ xt,
                                              half_t* __restrict__ x16) {
  const int idx = blockIdx.x * 256 + threadIdx.x;
  if (idx >= 512 * 128 * 64) return;
  const int kk = idx & 63;
  const int row = (idx >> 6) & 127;
  const int t = idx >> 13;
  float v = 0.f;
  if (kk < 47) v = xr[(row * 512 + t) * 47 + kk];
  else if (kk < 49) v = xt[(row * 512 + t) * 2 + (kk - 47)];
  x16[idx] = (half_t)v;
}

extern "C" void kernel_launch(void* const* d_in, const int* in_sizes, int n_in,
                              void* d_out, int out_size, void* d_ws,
                              size_t ws_size, hipStream_t stream) {
  const float* xr = (const float*)d_in[0];
  const float* xt = (const float*)d_in[1];
  const float* rWih0 = (const float*)d_in[2];
  const float* rWhh0 = (const float*)d_in[3];
  const float* r_b0 = (const float*)d_in[4];
  const float* rWih1 = (const float*)d_in[5];
  const float* rWhh1 = (const float*)d_in[6];
  const float* r_b1 = (const float*)d_in[7];
  const float* tWih0 = (const float*)d_in[8];
  const float* tWhh0 = (const float*)d_in[9];
  const float* t_b0 = (const float*)d_in[10];
  const float* tWih1 = (const float*)d_in[11];
  const float* tWhh1 = (const float*)d_in[12];
  const float* t_b1 = (const float*)d_in[13];
  const float* Wr = (const float*)d_in[14];
  const float* br = (const float*)d_in[15];
  const float* Wt = (const float*)d_in[16];
  const float* bt = (const float*)d_in[17];

  half_t* w16 = (half_t*)d_ws;
  float* cbase = (float*)((char*)d_ws + C_BYTE_OFF);
  unsigned* bar = (unsigned*)((char*)d_ws + BAR_BYTE_OFF);
  half_t* x16 = (half_t*)((char*)d_ws + X16_BYTE_OFF);
  float* out = (float*)d_out;
  int use_x16 = (ws_size >= WS_NEED_X16) ? 1 : 0;

  // zero h / ro / c / barrier state every call (deterministic)
  (void)hipMemsetAsync((char*)d_ws + STATE_BYTE_OFF, 0, STATE_BYTES, stream);

  conv_w<<<(W_TOTAL + 255) / 256, 256, 0, stream>>>(
      rWih0, rWhh0, rWih1, rWhh1, tWih0, tWhh0, tWih1, tWhh1, Wr, Wt, w16);
  if (use_x16)
    conv_x<<<(512 * 128 * 64) / 256, 256, 0, stream>>>(xr, xt, x16);

  adrnn_persist<<<NBLK, 256, 0, stream>>>(xr, xt, r_b0, r_b1, t_b0, t_b1, br,
                                          bt, w16, cbase, out, bar, x16,
                                          use_x16);
}

// Round 8
// 10823.436 us; speedup vs baseline: 1.6575x; 1.0035x over previous
//
#include <hip/hip_runtime.h>

// ---------------------------------------------------------------------------
// ADRNN persistent, hierarchical-barrier version (R6 compute, new barrier).
// 256 blocks x 256 threads (1 block/CU). Stages pipelined across ticks:
//   tick k: r0(t=k) | r1(k-1) | rout(k-2) | t0(k-3) | t1(k-4) | tout(k-5)
// Cross-block h/RO: inline-asm global_load_dwordx4 sc0 sc1 bursts (one LLC
// latency window per tick); h stores 8B relaxed agent atomics. Weights fp16
// [n][k] L2-resident per XCD via bid remap (bid = csLo*16 + bh*8 + stage*2
// + csHi -> stage pinned to an XCD pair, validated by R6 FETCH collapse).
// Barrier (new): monotonic LLC counters, hierarchical:
//   every block: 1 fetch_add to per-XCD arrival line (8 lines in parallel)
//   leaders (bid<8): poll own line -> 1 add to global line -> poll global
//                    (8 pollers) -> 1 add to per-XCD gen line
//   others: poll per-XCD gen line with slow pacing
// No resets (monotonic targets) -> no reset races, deadlock-free by
// construction given co-residency (1 block/CU, proven by R5/R6 completing).
// ---------------------------------------------------------------------------

typedef _Float16 half_t;
typedef _Float16 half8 __attribute__((ext_vector_type(8)));
typedef float floatx4 __attribute__((ext_vector_type(4)));
typedef unsigned long long ull_t;

// half-unit offsets inside d_ws
#define OFF_W0 0        // r_Wih0 padded  [2048][64]
#define OFF_W1 131072   // r_Whh0         [2048][512]
#define OFF_W2 1179648  // r_Wih1         [2048][512]
#define OFF_W3 2228224  // r_Whh1         [2048][512]
#define OFF_W4 3276800  // t_Wih0 cols0-48 padded [2048][64]
#define OFF_W5 3407872  // t_Wih0 cols49-95 padded [2048][64]
#define OFF_W6 3538944  // t_Whh0         [2048][512]
#define OFF_W7 4587520  // t_Wih1         [2048][512]
#define OFF_W8 5636096  // t_Whh1         [2048][512]
#define OFF_W9 6684672  // Wr padded      [48][512]
#define OFF_W10 6709248 // Wt padded      [16][512]
#define W_TOTAL 6717440
#define H_BASE  6717440              // h[4 cells][2 par][128][512] halves
#define RO_BASE 7241728              // rout16[2 par][128][64] halves
#define HALF_TOTAL 7258112
// byte offsets
#define STATE_BYTE_OFF (H_BASE * 2)          // 13434880
#define C_BYTE_OFF (HALF_TOTAL * 2)          // 14516224 (c: 4x[128][512] f32)
#define BAR_BYTE_OFF 15564800                // barrier state (4 KiB)
#define X16_BYTE_OFF (BAR_BYTE_OFF + 4096)   // optional x16 [512][128][64]
#define WS_NEED_X16 ((unsigned long long)X16_BYTE_OFF + 8388608ull)
#define STATE_BYTES (X16_BYTE_OFF - STATE_BYTE_OFF)  // h+ro+c+barrier

#define NBLK 256
#define TOUT_BASE (128 * 512 * 47)

__device__ __forceinline__ floatx4 mfma16(half8 a, half8 b, floatx4 c) {
  return __builtin_amdgcn_mfma_f32_16x16x32_f16(a, b, c, 0, 0, 0);
}

__device__ __forceinline__ float fast_sig(float x) {
  x = fminf(fmaxf(x, -30.f), 30.f);
  float e = __expf(-x);
  return __builtin_amdgcn_rcpf(1.f + e);
}
__device__ __forceinline__ float fast_tanh(float x) {
  x = fminf(fmaxf(x, -15.f), 15.f);
  float e = __expf(-2.f * x);
  return (1.f - e) * __builtin_amdgcn_rcpf(1.f + e);
}

// Issue N coherent 16B loads (LLC) in one burst; drain once afterwards.
template <int N>
__device__ __forceinline__ void coh_stage(half8 (&bb)[N], const half_t* p) {
#pragma unroll
  for (int ks = 0; ks < N; ++ks)
    asm volatile("global_load_dwordx4 %0, %1, off sc0 sc1"
                 : "=v"(bb[ks])
                 : "v"(p + ks * 32));
}
__device__ __forceinline__ void drain_vm() {
  asm volatile("s_waitcnt vmcnt(0)" ::: "memory");
  __builtin_amdgcn_sched_barrier(0);
}

__device__ __forceinline__ void store_h4_coh(half_t* p, half_t h0, half_t h1,
                                             half_t h2, half_t h3) {
  union { ull_t u; _Float16 h[4]; } x;
  x.h[0] = h0; x.h[1] = h1; x.h[2] = h2; x.h[3] = h3;
  __hip_atomic_store((ull_t*)p, x.u, __ATOMIC_RELAXED,
                     __HIP_MEMORY_SCOPE_AGENT);
}

// Poll a monotonic LLC counter until >= target. pace = s_sleep amount.
__device__ __forceinline__ void poll_llc(const unsigned* p, unsigned target,
                                         int pace) {
  for (;;) {
    unsigned v;
    asm volatile("global_load_dword %0, %1, off sc0 sc1\ns_waitcnt vmcnt(0)"
                 : "=v"(v) : "v"(p));
    if (v >= target) return;
    if (pace == 1) __builtin_amdgcn_s_sleep(1);
    else __builtin_amdgcn_s_sleep(3);
  }
}

// MFMA over staged B-fragments; W streamed with plain (L1/L2) loads.
// C/D: lane l -> col(batch)=l15, rows(gate hcols)=q*4+r.
template <int NT, int NSEG, int LDW>
__device__ __forceinline__ void gemm_staged(const half_t* __restrict__ W,
                                            const int* wrow,
                                            const half8 (&bb)[NSEG], int lk,
                                            int l15, floatx4 (&acc)[NT]) {
#pragma unroll
  for (int ks = 0; ks < NSEG; ++ks) {
    const int kb = ks * 32 + lk;
#pragma unroll
    for (int n = 0; n < NT; ++n) {
      half8 a = *(const half8*)(W + (long)(wrow[n] + l15) * LDW + kb);
      acc[n] = mfma16(a, bb[ks], acc[n]);
    }
  }
}

// K=64 gemm with plain (x16, L2) B loads.
__device__ __forceinline__ void gemm_plain2(const half_t* __restrict__ W,
                                            const int* wrow,
                                            const half_t* __restrict__ xb,
                                            int lk, int l15, floatx4 (&acc)[4]) {
#pragma unroll
  for (int ks = 0; ks < 2; ++ks) {
    const int kb = ks * 32 + lk;
    half8 b = *(const half8*)(xb + kb);
#pragma unroll
    for (int n = 0; n < 4; ++n) {
      half8 a = *(const half8*)(W + (long)(wrow[n] + l15) * 64 + kb);
      acc[n] = mfma16(a, b, acc[n]);
    }
  }
}

// Fallback X-gemm (no x16 buffer): B built from fp32 x_r/x_t gathers.
__device__ __forceinline__ void gemm_xf(const float* __restrict__ xr,
                                        const float* __restrict__ xt, int t,
                                        int batch, const half_t* __restrict__ W,
                                        const int* wrow, int lk, int l15,
                                        floatx4 (&acc)[4]) {
#pragma unroll
  for (int ks = 0; ks < 2; ++ks) {
    const int kb = ks * 32 + lk;
    half8 b;
    const long base = (long)batch * 512 + t;
#pragma unroll
    for (int j = 0; j < 8; ++j) {
      const int kk = kb + j;
      float f = 0.f;
      if (kk < 47) f = xr[base * 47 + kk];
      else if (kk < 49) f = xt[base * 2 + (kk - 47)];
      b[j] = (half_t)f;
    }
#pragma unroll
    for (int n = 0; n < 4; ++n) {
      half8 a = *(const half8*)(W + (long)(wrow[n] + l15) * 64 + kb);
      acc[n] = mfma16(a, b, acc[n]);
    }
  }
}

// LSTM epilogue: lane owns batch row `batch`, h-cols hcol0..hcol0+3.
__device__ __forceinline__ void lstm_epi_sw(floatx4 (&acc)[4],
                                            const float* __restrict__ bias,
                                            float* __restrict__ cst,
                                            half_t* __restrict__ hdst,
                                            int batch, int hcol0) {
  const floatx4 bI = *(const floatx4*)(bias + hcol0);
  const floatx4 bF = *(const floatx4*)(bias + 512 + hcol0);
  const floatx4 bG = *(const floatx4*)(bias + 1024 + hcol0);
  const floatx4 bO = *(const floatx4*)(bias + 1536 + hcol0);
  const int off = batch * 512 + hcol0;
  floatx4 cold = *(floatx4*)(cst + off);
  floatx4 cn;
  half_t hn[4];
#pragma unroll
  for (int r = 0; r < 4; ++r) {
    const float gi = acc[0][r] + bI[r];
    const float gf = acc[1][r] + bF[r];
    const float gg = acc[2][r] + bG[r];
    const float go = acc[3][r] + bO[r];
    cn[r] = fast_sig(gf) * cold[r] + fast_sig(gi) * fast_tanh(gg);
    hn[r] = (half_t)(fast_sig(go) * fast_tanh(cn[r]));
  }
  *(floatx4*)(cst + off) = cn;
  store_h4_coh(hdst + off, hn[0], hn[1], hn[2], hn[3]);
}

__global__ __launch_bounds__(256, 1) void adrnn_persist(
    const float* __restrict__ xr, const float* __restrict__ xt,
    const float* __restrict__ b_r0, const float* __restrict__ b_r1,
    const float* __restrict__ b_t0, const float* __restrict__ b_t1,
    const float* __restrict__ brv, const float* __restrict__ btv,
    half_t* __restrict__ w16, float* __restrict__ cbase,
    float* __restrict__ out, unsigned* bar, const half_t* __restrict__ x16,
    int use_x16) {
  const int bid = blockIdx.x;
  const int tid = threadIdx.x;
  const int lane = tid & 63;
  const int w = tid >> 6;
  const int l15 = lane & 15;
  const int q = lane >> 4;
  const int lk = q * 8;
  half_t* H = w16 + H_BASE;
  half_t* RO = w16 + RO_BASE;
#define HB(cell, p) (H + (((cell)*2 + (p)) << 16))

  // XCD-pinned decode: bid = csLo*16 + bh*8 + stage*2 + csHi
  const int stage = (bid & 7) >> 1;  // 0..3 -> XCDs {2s,2s+1}
  const int csHi = bid & 1;
  const int bh = (bid >> 3) & 1;
  const int csLo = bid >> 4;         // 0..15
  const int cs = csHi * 16 + csLo;   // 0..31
  const int sub = cs * 2 + bh;       // 0..63
  const int c0 = cs * 16;
  const int batch = bh * 64 + w * 16 + l15;
  const int hboff = batch * 512;
  const int hcol0 = c0 + q * 4;
  const int sd = (stage == 0) ? 0 : (stage == 1) ? 1 : (stage == 2) ? 3 : 4;
  int wrow[4] = {c0, 512 + c0, 1024 + c0, 1536 + c0};
  const int flat = sub * 4 + w;      // stage-0 spare-tile id

  // hierarchical barrier lines (monotonic, all-LLC)
  unsigned* larr = bar + (bid & 7) * 32;   // per-XCD arrival
  unsigned* garr = bar + 256;              // global arrival (leaders only)
  unsigned* lgen = bar + 288 + (bid & 7) * 32;  // per-XCD generation

  for (int k = 0; k < 517; ++k) {
    const int par = k & 1, pq = par ^ 1;
    const int t = k - sd;
    if (t >= 0 && t < 512) {
      floatx4 acc[4] = {};
      if (stage == 0) {        // r0: X @ Wih0^T + hr0 @ Whh0^T
        half8 b0[16];
        coh_stage<16>(b0, HB(0, pq) + hboff + lk);
        drain_vm();
        if (use_x16)
          gemm_plain2(w16 + OFF_W0, wrow, x16 + t * 8192 + batch * 64, lk, l15, acc);
        else
          gemm_xf(xr, xt, t, batch, w16 + OFF_W0, wrow, lk, l15, acc);
        gemm_staged<4, 16, 512>(w16 + OFF_W1, wrow, b0, lk, l15, acc);
        lstm_epi_sw(acc, b_r0, cbase + 0 * 65536, HB(0, par), batch, hcol0);
      } else if (stage == 1) { // r1
        half8 b0[16], b1[16];
        coh_stage<16>(b0, HB(0, pq) + hboff + lk);
        coh_stage<16>(b1, HB(1, pq) + hboff + lk);
        drain_vm();
        gemm_staged<4, 16, 512>(w16 + OFF_W2, wrow, b0, lk, l15, acc);
        gemm_staged<4, 16, 512>(w16 + OFF_W3, wrow, b1, lk, l15, acc);
        lstm_epi_sw(acc, b_r1, cbase + 1 * 65536, HB(1, par), batch, hcol0);
      } else if (stage == 2) { // t0: X + RO + ht0
        half8 bro[2], b2[16];
        coh_stage<2>(bro, RO + pq * 8192 + batch * 64 + lk);
        coh_stage<16>(b2, HB(2, pq) + hboff + lk);
        drain_vm();
        if (use_x16)
          gemm_plain2(w16 + OFF_W4, wrow, x16 + t * 8192 + batch * 64, lk, l15, acc);
        else
          gemm_xf(xr, xt, t, batch, w16 + OFF_W4, wrow, lk, l15, acc);
        gemm_staged<4, 2, 64>(w16 + OFF_W5, wrow, bro, lk, l15, acc);
        gemm_staged<4, 16, 512>(w16 + OFF_W6, wrow, b2, lk, l15, acc);
        lstm_epi_sw(acc, b_t0, cbase + 2 * 65536, HB(2, par), batch, hcol0);
      } else {                 // t1
        half8 b0[16], b1[16];
        coh_stage<16>(b0, HB(2, pq) + hboff + lk);
        coh_stage<16>(b1, HB(3, pq) + hboff + lk);
        drain_vm();
        gemm_staged<4, 16, 512>(w16 + OFF_W7, wrow, b0, lk, l15, acc);
        gemm_staged<4, 16, 512>(w16 + OFF_W8, wrow, b1, lk, l15, acc);
        lstm_epi_sw(acc, b_t1, cbase + 3 * 65536, HB(3, par), batch, hcol0);
      }
    }
    // rout/tout folded into stage-0 spare waves
    if (stage == 0 && flat < 32) {
      if (flat < 24) {  // rout: n-tile (0..2) x batch-tile (0..7)
        const int tr = k - 2;
        if (tr >= 0 && tr < 512) {
          const int n = flat >> 3, btl = flat & 7;
          const int rb = btl * 16 + l15;
          half8 bs[16];
          coh_stage<16>(bs, HB(1, pq) + rb * 512 + lk);
          drain_vm();
          int wr1[1] = {n * 16};
          floatx4 accr[1] = {};
          gemm_staged<1, 16, 512>(w16 + OFF_W9, wr1, bs, lk, l15, accr);
          const int wc0 = n * 16 + q * 4;
          half_t ro4[4];
#pragma unroll
          for (int r = 0; r < 4; ++r) {
            const int wc = wc0 + r;
            float v = 0.f;
            if (wc < 47) {
              v = accr[0][r] + brv[wc];
              out[((long)rb * 512 + tr) * 47 + wc] = v;
            }
            ro4[r] = (half_t)v;
          }
          store_h4_coh(RO + par * 8192 + rb * 64 + wc0, ro4[0], ro4[1], ro4[2], ro4[3]);
        }
      } else {          // tout: batch-tile (0..7)
        const int tt = k - 5;
        if (tt >= 0 && tt < 512) {
          const int btl = flat - 24;
          const int rb = btl * 16 + l15;
          half8 bs[16];
          coh_stage<16>(bs, HB(3, pq) + rb * 512 + lk);
          drain_vm();
          int wt1[1] = {0};
          floatx4 accw[1] = {};
          gemm_staged<1, 16, 512>(w16 + OFF_W10, wt1, bs, lk, l15, accw);
          if (q == 0) {
#pragma unroll
            for (int r = 0; r < 2; ++r)
              out[TOUT_BASE + ((long)rb * 512 + tt) * 2 + r] = accw[0][r] + btv[r];
          }
        }
      }
    }
    // ---- hierarchical barrier (monotonic LLC counters, no resets) ----
    asm volatile("s_waitcnt vmcnt(0)" ::: "memory");
    __syncthreads();
    if (tid == 0) {
      const unsigned ku = (unsigned)k + 1u;
      (void)__hip_atomic_fetch_add(larr, 1u, __ATOMIC_RELAXED,
                                   __HIP_MEMORY_SCOPE_AGENT);
      if (bid < 8) {
        poll_llc(larr, 32u * ku, 1);   // own XCD's 32 arrivals
        (void)__hip_atomic_fetch_add(garr, 1u, __ATOMIC_RELAXED,
                                     __HIP_MEMORY_SCOPE_AGENT);
        poll_llc(garr, 8u * ku, 1);    // all 8 leaders arrived
        (void)__hip_atomic_fetch_add(lgen, 1u, __ATOMIC_RELAXED,
                                     __HIP_MEMORY_SCOPE_AGENT);
      } else {
        poll_llc(lgen, ku, 3);         // per-XCD broadcast, slow pacing
      }
    }
    __syncthreads();
    asm volatile("" ::: "memory");  // no compiler reordering across the tick
  }
#undef HB
}

// fp32 -> fp16 weight conversion into [n][k] layout with zero padding.
__global__ __launch_bounds__(256) void conv_w(
    const float* __restrict__ rWih0, const float* __restrict__ rWhh0,
    const float* __restrict__ rWih1, const float* __restrict__ rWhh1,
    const float* __restrict__ tWih0, const float* __restrict__ tWhh0,
    const float* __restrict__ tWih1, const float* __restrict__ tWhh1,
    const float* __restrict__ Wr, const float* __restrict__ Wt,
    half_t* __restrict__ w16) {
  const int idx = blockIdx.x * 256 + threadIdx.x;
  if (idx >= W_TOTAL) return;
  float v = 0.f;
  if (idx < OFF_W1) {
    int n = idx >> 6, kk = idx & 63;
    if (kk < 49) v = rWih0[n * 49 + kk];
  } else if (idx < OFF_W2) {
    int r = idx - OFF_W1; v = rWhh0[r];
  } else if (idx < OFF_W3) {
    int r = idx - OFF_W2; v = rWih1[r];
  } else if (idx < OFF_W4) {
    int r = idx - OFF_W3; v = rWhh1[r];
  } else if (idx < OFF_W5) {
    int r = idx - OFF_W4; int n = r >> 6, kk = r & 63;
    if (kk < 49) v = tWih0[n * 96 + kk];
  } else if (idx < OFF_W6) {
    int r = idx - OFF_W5; int n = r >> 6, kk = r & 63;
    if (kk < 47) v = tWih0[n * 96 + 49 + kk];
  } else if (idx < OFF_W7) {
    int r = idx - OFF_W6; v = tWhh0[r];
  } else if (idx < OFF_W8) {
    int r = idx - OFF_W7; v = tWih1[r];
  } else if (idx < OFF_W9) {
    int r = idx - OFF_W8; v = tWhh1[r];
  } else if (idx < OFF_W10) {
    int r = idx - OFF_W9; int n = r >> 9, kk = r & 511;
    if (n < 47) v = Wr[n * 512 + kk];
  } else {
    int r = idx - OFF_W10; int n = r >> 9, kk = r & 511;
    if (n < 2) v = Wt[n * 512 + kk];
  }
  w16[idx] = (half_t)v;
}

// fp32 x_r/x_t -> fp16 [t][128][64] (cols 0..46 = x_r, 47..48 = x_t, rest 0)
__global__ __launch_bounds__(256) void conv_x(const float* __restrict__ xr,
                                              const float* __restrict__ xt,
                                              half_t* __restrict__ x16) {
  const int idx = blockIdx.x * 256 + threadIdx.x;
  if (idx >= 512 * 128 * 64) return;
  const int kk = idx & 63;
  const int row = (idx >> 6) & 127;
  const int t = idx >> 13;
  float v = 0.f;
  if (kk < 47) v = xr[(row * 512 + t) * 47 + kk];
  else if (kk < 49) v = xt[(row * 512 + t) * 2 + (kk - 47)];
  x16[idx] = (half_t)v;
}

extern "C" void kernel_launch(void* const* d_in, const int* in_sizes, int n_in,
                              void* d_out, int out_size, void* d_ws,
                              size_t ws_size, hipStream_t stream) {
  const float* xr = (const float*)d_in[0];
  const float* xt = (const float*)d_in[1];
  const float* rWih0 = (const float*)d_in[2];
  const float* rWhh0 = (const float*)d_in[3];
  const float* r_b0 = (const float*)d_in[4];
  const float* rWih1 = (const float*)d_in[5];
  const float* rWhh1 = (const float*)d_in[6];
  const float* r_b1 = (const float*)d_in[7];
  const float* tWih0 = (const float*)d_in[8];
  const float* tWhh0 = (const float*)d_in[9];
  const float* t_b0 = (const float*)d_in[10];
  const float* tWih1 = (const float*)d_in[11];
  const float* tWhh1 = (const float*)d_in[12];
  const float* t_b1 = (const float*)d_in[13];
  const float* Wr = (const float*)d_in[14];
  const float* br = (const float*)d_in[15];
  const float* Wt = (const float*)d_in[16];
  const float* bt = (const float*)d_in[17];

  half_t* w16 = (half_t*)d_ws;
  float* cbase = (float*)((char*)d_ws + C_BYTE_OFF);
  unsigned* bar = (unsigned*)((char*)d_ws + BAR_BYTE_OFF);
  half_t* x16 = (half_t*)((char*)d_ws + X16_BYTE_OFF);
  float* out = (float*)d_out;
  int use_x16 = (ws_size >= WS_NEED_X16) ? 1 : 0;

  // zero h / ro / c / barrier state every call (deterministic)
  (void)hipMemsetAsync((char*)d_ws + STATE_BYTE_OFF, 0, STATE_BYTES, stream);

  conv_w<<<(W_TOTAL + 255) / 256, 256, 0, stream>>>(
      rWih0, rWhh0, rWih1, rWhh1, tWih0, tWhh0, tWih1, tWhh1, Wr, Wt, w16);
  if (use_x16)
    conv_x<<<(512 * 128 * 64) / 256, 256, 0, stream>>>(xr, xt, x16);

  adrnn_persist<<<NBLK, 256, 0, stream>>>(xr, xt, r_b0, r_b1, t_b0, t_b1, br,
                                          bt, w16, cbase, out, bar, x16,
                                          use_x16);
}

// Round 11
// 9214.277 us; speedup vs baseline: 1.9470x; 1.1746x over previous
//
#include <hip/hip_runtime.h>

// ---------------------------------------------------------------------------
// ADRNN persistent R11 = R10 with compile fixes (dead template removed,
// poll pace as template constant). Design summary:
// 256 blocks x 256 threads (1 block/CU). Stages pipelined across ticks:
//   tick k: r0(t=k) | r1(k-1) | rout(k-2) | t0(k-3) | t1(k-4) | tout(k-5)
// Block tile: (4 gates x 64 hcols) x 16 batch. bid = ((hg&3)*8+bg)*8 +
// stage*2 + (hg>>2) -> XCD(bid%8)=stage*2+hgHi, weight slice 1-2MB/XCD
// stays L2-resident. Per tick each block stages its 16-batch-row h slab(s)
// (16KB each) ONCE into static LDS via cooperative sc0 sc1 burst +
// XOR-swizzled ds_write (conflict-free ds_read_b128 B-frags). Weights
// stream from L2 (plain cached loads). h stores: 8B relaxed agent atomics.
// Barrier: hierarchical monotonic-LLC counters (R8-proven).
// ---------------------------------------------------------------------------

typedef _Float16 half_t;
typedef _Float16 half8 __attribute__((ext_vector_type(8)));
typedef float floatx4 __attribute__((ext_vector_type(4)));
typedef unsigned long long ull_t;

// half-unit offsets inside d_ws
#define OFF_W0 0        // r_Wih0 padded  [2048][64]
#define OFF_W1 131072   // r_Whh0         [2048][512]
#define OFF_W2 1179648  // r_Wih1         [2048][512]
#define OFF_W3 2228224  // r_Whh1         [2048][512]
#define OFF_W4 3276800  // t_Wih0 cols0-48 padded [2048][64]
#define OFF_W5 3407872  // t_Wih0 cols49-95 padded [2048][64]
#define OFF_W6 3538944  // t_Whh0         [2048][512]
#define OFF_W7 4587520  // t_Wih1         [2048][512]
#define OFF_W8 5636096  // t_Whh1         [2048][512]
#define OFF_W9 6684672  // Wr padded      [48][512]
#define OFF_W10 6709248 // Wt padded      [16][512]
#define W_TOTAL 6717440
#define H_BASE  6717440              // h[4 cells][2 par][128][512] halves
#define RO_BASE 7241728              // rout16[2 par][128][64] halves
#define HALF_TOTAL 7258112
// byte offsets
#define STATE_BYTE_OFF (H_BASE * 2)          // 13434880
#define C_BYTE_OFF (HALF_TOTAL * 2)          // 14516224 (c: 4x[128][512] f32)
#define BAR_BYTE_OFF 15564800                // barrier state (4 KiB)
#define X16_BYTE_OFF (BAR_BYTE_OFF + 4096)   // optional x16 [512][128][64]
#define WS_NEED_X16 ((unsigned long long)X16_BYTE_OFF + 8388608ull)
#define STATE_BYTES (X16_BYTE_OFF - STATE_BYTE_OFF)  // h+ro+c+barrier

#define NBLK 256
#define TOUT_BASE (128 * 512 * 47)

__device__ __forceinline__ floatx4 mfma16(half8 a, half8 b, floatx4 c) {
  return __builtin_amdgcn_mfma_f32_16x16x32_f16(a, b, c, 0, 0, 0);
}
__device__ __forceinline__ float fast_sig(float x) {
  x = fminf(fmaxf(x, -30.f), 30.f);
  float e = __expf(-x);
  return __builtin_amdgcn_rcpf(1.f + e);
}
__device__ __forceinline__ float fast_tanh(float x) {
  x = fminf(fmaxf(x, -15.f), 15.f);
  float e = __expf(-2.f * x);
  return (1.f - e) * __builtin_amdgcn_rcpf(1.f + e);
}

// LLC-coherent 16B burst loads
template <int N>
__device__ __forceinline__ void coh_stage(half8 (&bb)[N], const half_t* p) {
#pragma unroll
  for (int ks = 0; ks < N; ++ks)
    asm volatile("global_load_dwordx4 %0, %1, off sc0 sc1"
                 : "=v"(bb[ks]) : "v"(p + ks * 32));
}
__device__ __forceinline__ void drain_vm() {
  asm volatile("s_waitcnt vmcnt(0)" ::: "memory");
  __builtin_amdgcn_sched_barrier(0);
}
__device__ __forceinline__ void store_h4_coh(half_t* p, half_t h0, half_t h1,
                                             half_t h2, half_t h3) {
  union { ull_t u; _Float16 h[4]; } x;
  x.h[0] = h0; x.h[1] = h1; x.h[2] = h2; x.h[3] = h3;
  __hip_atomic_store((ull_t*)p, x.u, __ATOMIC_RELAXED,
                     __HIP_MEMORY_SCOPE_AGENT);
}
// poll monotonic LLC counter until >= target; PACE is compile-time constant
template <int PACE>
__device__ __forceinline__ void poll_llc(const unsigned* p, unsigned target) {
  for (;;) {
    unsigned v;
    asm volatile("global_load_dword %0, %1, off sc0 sc1\ns_waitcnt vmcnt(0)"
                 : "=v"(v) : "v"(p));
    if (v >= target) return;
    __builtin_amdgcn_s_sleep(PACE);
  }
}

// Cooperative slab staging: 16 rows x 512 halves (16KB) -> LDS, XOR-swizzled.
__device__ __forceinline__ void slab_issue(half8 (&tmp)[4],
                                           const half_t* __restrict__ src,
                                           int tid) {
#pragma unroll
  for (int j = 0; j < 4; ++j) {
    const int u = tid + j * 256;
    asm volatile("global_load_dwordx4 %0, %1, off sc0 sc1"
                 : "=v"(tmp[j]) : "v"(src + (u >> 6) * 512 + (u & 63) * 8));
  }
}
__device__ __forceinline__ void slab_write(char* base, const half8 (&tmp)[4],
                                           int tid) {
#pragma unroll
  for (int j = 0; j < 4; ++j) {
    const int u = tid + j * 256;
    const int row = u >> 6, seg = u & 63;
    *(half8*)(base + row * 1024 + ((seg * 16) ^ ((row & 7) << 4))) = tmp[j];
  }
}

// GEMM: B-frags from swizzled LDS slab, A (weights) streamed from L2.
// C/D: lane l -> col(batch)=l15, rows(gate hcols)=q*4+r.
template <int NT, int NSEG, int LDW>
__device__ __forceinline__ void gemm_lb(const half_t* __restrict__ W,
                                        const int* wrow, const char* ldsb,
                                        int lk, int q, int l15,
                                        floatx4 (&acc)[NT]) {
  const int bbase = l15 * 1024;
  const int bxor = (l15 & 7) << 4;
#pragma unroll
  for (int ks = 0; ks < NSEG; ++ks) {
    const int kb = ks * 32 + lk;
    half8 b = *(const half8*)(ldsb + bbase + ((q * 16 + ks * 64) ^ bxor));
#pragma unroll
    for (int n = 0; n < NT; ++n) {
      half8 a = *(const half8*)(W + (long)(wrow[n] + l15) * LDW + kb);
      acc[n] = mfma16(a, b, acc[n]);
    }
  }
}

// GEMM with register B-frags (RO, spare rout/tout).
template <int NT, int NSEG, int LDW>
__device__ __forceinline__ void gemm_regB(const half_t* __restrict__ W,
                                          const int* wrow,
                                          const half8 (&bb)[NSEG], int lk,
                                          int l15, floatx4 (&acc)[NT]) {
#pragma unroll
  for (int ks = 0; ks < NSEG; ++ks) {
    const int kb = ks * 32 + lk;
#pragma unroll
    for (int n = 0; n < NT; ++n) {
      half8 a = *(const half8*)(W + (long)(wrow[n] + l15) * LDW + kb);
      acc[n] = mfma16(a, bb[ks], acc[n]);
    }
  }
}

// K=64 X gemm with plain cached B loads from x16.
__device__ __forceinline__ void gemm_x16(const half_t* __restrict__ W,
                                         const int* wrow,
                                         const half_t* __restrict__ xb, int lk,
                                         int l15, floatx4 (&acc)[4]) {
#pragma unroll
  for (int ks = 0; ks < 2; ++ks) {
    const int kb = ks * 32 + lk;
    half8 b = *(const half8*)(xb + kb);
#pragma unroll
    for (int n = 0; n < 4; ++n) {
      half8 a = *(const half8*)(W + (long)(wrow[n] + l15) * 64 + kb);
      acc[n] = mfma16(a, b, acc[n]);
    }
  }
}
// Fallback X gemm from fp32 inputs.
__device__ __forceinline__ void gemm_xf(const float* __restrict__ xr,
                                        const float* __restrict__ xt, int t,
                                        int batch, const half_t* __restrict__ W,
                                        const int* wrow, int lk, int l15,
                                        floatx4 (&acc)[4]) {
#pragma unroll
  for (int ks = 0; ks < 2; ++ks) {
    const int kb = ks * 32 + lk;
    half8 b;
    const long base = (long)batch * 512 + t;
#pragma unroll
    for (int j = 0; j < 8; ++j) {
      const int kk = kb + j;
      float f = 0.f;
      if (kk < 47) f = xr[base * 47 + kk];
      else if (kk < 49) f = xt[base * 2 + (kk - 47)];
      b[j] = (half_t)f;
    }
#pragma unroll
    for (int n = 0; n < 4; ++n) {
      half8 a = *(const half8*)(W + (long)(wrow[n] + l15) * 64 + kb);
      acc[n] = mfma16(a, b, acc[n]);
    }
  }
}

// LSTM epilogue: lane owns batch row `batch`, h-cols hcol0..hcol0+3.
__device__ __forceinline__ void lstm_epi_sw(floatx4 (&acc)[4],
                                            const float* __restrict__ bias,
                                            float* __restrict__ cst,
                                            half_t* __restrict__ hdst,
                                            int batch, int hcol0) {
  const floatx4 bI = *(const floatx4*)(bias + hcol0);
  const floatx4 bF = *(const floatx4*)(bias + 512 + hcol0);
  const floatx4 bG = *(const floatx4*)(bias + 1024 + hcol0);
  const floatx4 bO = *(const floatx4*)(bias + 1536 + hcol0);
  const int off = batch * 512 + hcol0;
  floatx4 cold = *(floatx4*)(cst + off);
  floatx4 cn;
  half_t hn[4];
#pragma unroll
  for (int r = 0; r < 4; ++r) {
    const float gi = acc[0][r] + bI[r];
    const float gf = acc[1][r] + bF[r];
    const float gg = acc[2][r] + bG[r];
    const float go = acc[3][r] + bO[r];
    cn[r] = fast_sig(gf) * cold[r] + fast_sig(gi) * fast_tanh(gg);
    hn[r] = (half_t)(fast_sig(go) * fast_tanh(cn[r]));
  }
  *(floatx4*)(cst + off) = cn;
  store_h4_coh(hdst + off, hn[0], hn[1], hn[2], hn[3]);
}

__global__ __launch_bounds__(256, 1) void adrnn_persist(
    const float* __restrict__ xr, const float* __restrict__ xt,
    const float* __restrict__ b_r0, const float* __restrict__ b_r1,
    const float* __restrict__ b_t0, const float* __restrict__ b_t1,
    const float* __restrict__ brv, const float* __restrict__ btv,
    half_t* __restrict__ w16, float* __restrict__ cbase,
    float* __restrict__ out, unsigned* bar, const half_t* __restrict__ x16,
    int use_x16) {
  __shared__ half8 lds_v[2048];  // 32KB: two 16KB swizzled B slabs
  char* lds0 = (char*)lds_v;
  char* lds1 = lds0 + 16384;

  const int bid = blockIdx.x;
  const int tid = threadIdx.x;
  const int lane = tid & 63;
  const int w = tid >> 6;
  const int l15 = lane & 15;
  const int q = lane >> 4;
  const int lk = q * 8;
  half_t* H = w16 + H_BASE;
  half_t* RO = w16 + RO_BASE;
#define HB(cell, p) (H + (((cell)*2 + (p)) << 16))

  // decode: bid = ((hg&3)*8 + bg)*8 + stage*2 + (hg>>2)
  const int stage = (bid & 7) >> 1;
  const int hgHi = bid & 1;
  const int rr = bid >> 3;        // 0..31
  const int hgLo = rr >> 3;       // 0..3
  const int bg = rr & 7;          // 0..7
  const int hg = hgHi * 4 + hgLo; // 0..7 (64 hcols each)
  const int c0w = hg * 64 + w * 16;
  const int b0 = bg * 16;
  const int batch = b0 + l15;
  const int hcol0 = c0w + q * 4;
  const int sd = (stage == 0) ? 0 : (stage == 1) ? 1 : (stage == 2) ? 3 : 4;
  int wrow[4] = {c0w, 512 + c0w, 1024 + c0w, 1536 + c0w};
  // spares: stage-0 blocks with hg<2; 64 waves, first 32 used
  const int flat = (hg * 8 + bg) * 4 + w;
  const bool is_spare = (stage == 0 && hg < 2 && flat < 32);

  // hierarchical barrier lines (monotonic LLC)
  unsigned* larr = bar + (bid & 7) * 32;
  unsigned* garr = bar + 256;
  unsigned* lgen = bar + 288 + (bid & 7) * 32;

  for (int k = 0; k < 517; ++k) {
    const int par = k & 1, pq = par ^ 1;
    const int t = k - sd;
    const bool valid = (t >= 0 && t < 512);

    // ---- cooperative LDS staging of B slabs (16 rows x 1KB each) ----
    if (valid) {
      half8 s0[4], s1[4];
      if (stage == 0) {
        slab_issue(s0, HB(0, pq) + b0 * 512, tid);
        drain_vm();
        slab_write(lds0, s0, tid);
      } else if (stage == 1) {
        slab_issue(s0, HB(0, pq) + b0 * 512, tid);
        slab_issue(s1, HB(1, pq) + b0 * 512, tid);
        drain_vm();
        slab_write(lds0, s0, tid);
        slab_write(lds1, s1, tid);
      } else if (stage == 2) {
        slab_issue(s0, HB(2, pq) + b0 * 512, tid);
        drain_vm();
        slab_write(lds0, s0, tid);
      } else {
        slab_issue(s0, HB(2, pq) + b0 * 512, tid);
        slab_issue(s1, HB(3, pq) + b0 * 512, tid);
        drain_vm();
        slab_write(lds0, s0, tid);
        slab_write(lds1, s1, tid);
      }
    }
    __syncthreads();

    // ---- main compute ----
    if (valid) {
      floatx4 acc[4] = {};
      if (stage == 0) {        // r0: X @ Wih0^T + h0 @ Whh0^T
        if (use_x16)
          gemm_x16(w16 + OFF_W0, wrow, x16 + (long)t * 8192 + batch * 64, lk, l15, acc);
        else
          gemm_xf(xr, xt, t, batch, w16 + OFF_W0, wrow, lk, l15, acc);
        gemm_lb<4, 16, 512>(w16 + OFF_W1, wrow, lds0, lk, q, l15, acc);
        lstm_epi_sw(acc, b_r0, cbase + 0 * 65536, HB(0, par), batch, hcol0);
      } else if (stage == 1) { // r1
        gemm_lb<4, 16, 512>(w16 + OFF_W2, wrow, lds0, lk, q, l15, acc);
        gemm_lb<4, 16, 512>(w16 + OFF_W3, wrow, lds1, lk, q, l15, acc);
        lstm_epi_sw(acc, b_r1, cbase + 1 * 65536, HB(1, par), batch, hcol0);
      } else if (stage == 2) { // t0: X + RO + h2
        half8 bro[2];
        coh_stage<2>(bro, RO + pq * 8192 + batch * 64 + lk);
        drain_vm();
        if (use_x16)
          gemm_x16(w16 + OFF_W4, wrow, x16 + (long)t * 8192 + batch * 64, lk, l15, acc);
        else
          gemm_xf(xr, xt, t, batch, w16 + OFF_W4, wrow, lk, l15, acc);
        gemm_regB<4, 2, 64>(w16 + OFF_W5, wrow, bro, lk, l15, acc);
        gemm_lb<4, 16, 512>(w16 + OFF_W6, wrow, lds0, lk, q, l15, acc);
        lstm_epi_sw(acc, b_t0, cbase + 2 * 65536, HB(2, par), batch, hcol0);
      } else {                 // t1
        gemm_lb<4, 16, 512>(w16 + OFF_W7, wrow, lds0, lk, q, l15, acc);
        gemm_lb<4, 16, 512>(w16 + OFF_W8, wrow, lds1, lk, q, l15, acc);
        lstm_epi_sw(acc, b_t1, cbase + 3 * 65536, HB(3, par), batch, hcol0);
      }
    }

    // ---- rout/tout on stage-0 spare waves ----
    if (is_spare) {
      if (flat < 24) {  // rout: 3 n-tiles x 8 batch-tiles, t = k-2
        const int tr = k - 2;
        if (tr >= 0 && tr < 512) {
          const int n = flat >> 3, btl = flat & 7;
          const int rb = btl * 16 + l15;
          half8 bs[16];
          coh_stage<16>(bs, HB(1, pq) + rb * 512 + lk);
          drain_vm();
          int wr1[1] = {n * 16};
          floatx4 accr[1] = {};
          gemm_regB<1, 16, 512>(w16 + OFF_W9, wr1, bs, lk, l15, accr);
          const int wc0 = n * 16 + q * 4;
          half_t ro4[4];
#pragma unroll
          for (int r = 0; r < 4; ++r) {
            const int wc = wc0 + r;
            float v = 0.f;
            if (wc < 47) {
              v = accr[0][r] + brv[wc];
              out[((long)rb * 512 + tr) * 47 + wc] = v;
            }
            ro4[r] = (half_t)v;
          }
          store_h4_coh(RO + par * 8192 + rb * 64 + wc0, ro4[0], ro4[1], ro4[2], ro4[3]);
        }
      } else {          // tout: 8 batch-tiles, t = k-5
        const int tt = k - 5;
        if (tt >= 0 && tt < 512) {
          const int btl = flat - 24;
          const int rb = btl * 16 + l15;
          half8 bs[16];
          coh_stage<16>(bs, HB(3, pq) + rb * 512 + lk);
          drain_vm();
          int wt1[1] = {0};
          floatx4 accw[1] = {};
          gemm_regB<1, 16, 512>(w16 + OFF_W10, wt1, bs, lk, l15, accw);
          if (q == 0) {
#pragma unroll
            for (int r = 0; r < 2; ++r)
              out[TOUT_BASE + ((long)rb * 512 + tt) * 2 + r] = accw[0][r] + btv[r];
          }
        }
      }
    }

    // ---- hierarchical barrier (monotonic LLC counters; R8-proven) ----
    asm volatile("s_waitcnt vmcnt(0)" ::: "memory");
    __syncthreads();
    if (tid == 0) {
      const unsigned ku = (unsigned)k + 1u;
      (void)__hip_atomic_fetch_add(larr, 1u, __ATOMIC_RELAXED,
                                   __HIP_MEMORY_SCOPE_AGENT);
      if (bid < 8) {
        poll_llc<1>(larr, 32u * ku);
        (void)__hip_atomic_fetch_add(garr, 1u, __ATOMIC_RELAXED,
                                     __HIP_MEMORY_SCOPE_AGENT);
        poll_llc<1>(garr, 8u * ku);
        (void)__hip_atomic_fetch_add(lgen, 1u, __ATOMIC_RELAXED,
                                     __HIP_MEMORY_SCOPE_AGENT);
      } else {
        poll_llc<3>(lgen, ku);
      }
    }
    __syncthreads();
    asm volatile("" ::: "memory");
  }
#undef HB
}

// fp32 -> fp16 weight conversion into [n][k] layout with zero padding.
__global__ __launch_bounds__(256) void conv_w(
    const float* __restrict__ rWih0, const float* __restrict__ rWhh0,
    const float* __restrict__ rWih1, const float* __restrict__ rWhh1,
    const float* __restrict__ tWih0, const float* __restrict__ tWhh0,
    const float* __restrict__ tWih1, const float* __restrict__ tWhh1,
    const float* __restrict__ Wr, const float* __restrict__ Wt,
    half_t* __restrict__ w16) {
  const int idx = blockIdx.x * 256 + threadIdx.x;
  if (idx >= W_TOTAL) return;
  float v = 0.f;
  if (idx < OFF_W1) {
    int n = idx >> 6, kk = idx & 63;
    if (kk < 49) v = rWih0[n * 49 + kk];
  } else if (idx < OFF_W2) {
    int r = idx - OFF_W1; v = rWhh0[r];
  } else if (idx < OFF_W3) {
    int r = idx - OFF_W2; v = rWih1[r];
  } else if (idx < OFF_W4) {
    int r = idx - OFF_W3; v = rWhh1[r];
  } else if (idx < OFF_W5) {
    int r = idx - OFF_W4; int n = r >> 6, kk = r & 63;
    if (kk < 49) v = tWih0[n * 96 + kk];
  } else if (idx < OFF_W6) {
    int r = idx - OFF_W5; int n = r >> 6, kk = r & 63;
    if (kk < 47) v = tWih0[n * 96 + 49 + kk];
  } else if (idx < OFF_W7) {
    int r = idx - OFF_W6; v = tWhh0[r];
  } else if (idx < OFF_W8) {
    int r = idx - OFF_W7; v = tWih1[r];
  } else if (idx < OFF_W9) {
    int r = idx - OFF_W8; v = tWhh1[r];
  } else if (idx < OFF_W10) {
    int r = idx - OFF_W9; int n = r >> 9, kk = r & 511;
    if (n < 47) v = Wr[n * 512 + kk];
  } else {
    int r = idx - OFF_W10; int n = r >> 9, kk = r & 511;
    if (n < 2) v = Wt[n * 512 + kk];
  }
  w16[idx] = (half_t)v;
}

// fp32 x_r/x_t -> fp16 [t][128][64] (cols 0..46 = x_r, 47..48 = x_t, rest 0)
__global__ __launch_bounds__(256) void conv_x(const float* __restrict__ xr,
                                              const float* __restrict__ xt,
                                              half_t* __restrict__ x16) {
  const int idx = blockIdx.x * 256 + threadIdx.x;
  if (idx >= 512 * 128 * 64) return;
  const int kk = idx & 63;
  const int row = (idx >> 6) & 127;
  const int t = idx >> 13;
  float v = 0.f;
  if (kk < 47) v = xr[(row * 512 + t) * 47 + kk];
  else if (kk < 49) v = xt[(row * 512 + t) * 2 + (kk - 47)];
  x16[idx] = (half_t)v;
}

extern "C" void kernel_launch(void* const* d_in, const int* in_sizes, int n_in,
                              void* d_out, int out_size, void* d_ws,
                              size_t ws_size, hipStream_t stream) {
  const float* xr = (const float*)d_in[0];
  const float* xt = (const float*)d_in[1];
  const float* rWih0 = (const float*)d_in[2];
  const float* rWhh0 = (const float*)d_in[3];
  const float* r_b0 = (const float*)d_in[4];
  const float* rWih1 = (const float*)d_in[5];
  const float* rWhh1 = (const float*)d_in[6];
  const float* r_b1 = (const float*)d_in[7];
  const float* tWih0 = (const float*)d_in[8];
  const float* tWhh0 = (const float*)d_in[9];
  const float* t_b0 = (const float*)d_in[10];
  const float* tWih1 = (const float*)d_in[11];
  const float* tWhh1 = (const float*)d_in[12];
  const float* t_b1 = (const float*)d_in[13];
  const float* Wr = (const float*)d_in[14];
  const float* br = (const float*)d_in[15];
  const float* Wt = (const float*)d_in[16];
  const float* bt = (const float*)d_in[17];

  half_t* w16 = (half_t*)d_ws;
  float* cbase = (float*)((char*)d_ws + C_BYTE_OFF);
  unsigned* bar = (unsigned*)((char*)d_ws + BAR_BYTE_OFF);
  half_t* x16 = (half_t*)((char*)d_ws + X16_BYTE_OFF);
  float* out = (float*)d_out;
  int use_x16 = (ws_size >= WS_NEED_X16) ? 1 : 0;

  // zero h / ro / c / barrier state every call (deterministic)
  (void)hipMemsetAsync((char*)d_ws + STATE_BYTE_OFF, 0, STATE_BYTES, stream);

  conv_w<<<(W_TOTAL + 255) / 256, 256, 0, stream>>>(
      rWih0, rWhh0, rWih1, rWhh1, tWih0, tWhh0, tWih1, tWhh1, Wr, Wt, w16);
  if (use_x16)
    conv_x<<<(512 * 128 * 64) / 256, 256, 0, stream>>>(xr, xt, x16);

  adrnn_persist<<<NBLK, 256, 0, stream>>>(xr, xt, r_b0, r_b1, t_b0, t_b1, br,
                                          bt, w16, cbase, out, bar, x16,
                                          use_x16);
}